// Round 11
// baseline (639.206 us; speedup 1.0000x reference)
//
#include <hip/hip_runtime.h>
#include <hip/hip_bf16.h>

#define FLAT   2048
#define EDG    131072
#define NEF    64
#define EPA    32

typedef short  frag8  __attribute__((ext_vector_type(8)));   // 8 bf16 = 4 VGPRs
typedef float  f32x16 __attribute__((ext_vector_type(16)));  // MFMA 32x32 acc

__device__ __forceinline__ float siluf(float x){ return x / (1.f + __expf(-x)); }

__device__ __forceinline__ uint4 pack8(const float v[8]){
    union { uint4 u; __hip_bfloat16 h[8]; } r;
    #pragma unroll
    for (int i=0;i<8;i++) r.h[i] = __float2bfloat16(v[i]);
    return r.u;
}

// ---------------- tiny helpers ----------------
__global__ void k_hist(const int* __restrict__ src, int* __restrict__ cnt){
    int e = blockIdx.x*256 + threadIdx.x;
    if (e < EDG) atomicAdd(&cnt[src[e]], 1);
}

__global__ __launch_bounds__(1024) void k_scan(const int* __restrict__ cnt,
                                               int* __restrict__ off, int* __restrict__ cur){
    __shared__ int s[2048];
    const int tid = threadIdx.x;
    s[tid]      = cnt[tid];
    s[tid+1024] = cnt[tid+1024];
    __syncthreads();
    for (int d=1; d<2048; d<<=1){
        int a = (tid      >= d) ? s[tid      -d] : 0;
        int b = (tid+1024 >= d) ? s[tid+1024 -d] : 0;
        __syncthreads();
        s[tid]      += a;
        s[tid+1024] += b;
        __syncthreads();
    }
    int e0 = (tid==0) ? 0 : s[tid-1];
    int e1 = s[tid+1023];
    off[tid]      = e0;  cur[tid]      = e0;
    off[tid+1024] = e1;  cur[tid+1024] = e1;
    if (tid==0) off[2048] = s[2047];
}

__global__ void k_scatter(const int* __restrict__ src, int* __restrict__ cur,
                          int* __restrict__ elist){
    int e = blockIdx.x*256 + threadIdx.x;
    if (e < EDG){
        int p = atomicAdd(&cur[src[e]], 1);
        elist[p] = e;
    }
}

// merged prep: blocks [0,576): cvtW2 ; [576,752): cvtW1s ; [752,816): scales
__global__ __launch_bounds__(256) void k_prep(
    const float* __restrict__ W2, __hip_bfloat16* __restrict__ W2B,
    const float* __restrict__ gW1, const float* __restrict__ vwW1,
    __hip_bfloat16* __restrict__ gW1B, __hip_bfloat16* __restrict__ vwW1B,
    const float* __restrict__ eW1, const float* __restrict__ eb1,
    const float* __restrict__ eW2, const float* __restrict__ eb2,
    const float* __restrict__ e_feat, float* __restrict__ sfull)
{
    const int b = blockIdx.x;
    if (b < 576){
        int t = b*256 + threadIdx.x;
        if (t >= 36*8*512) return;
        int j    = t & 7;
        int lane = (t>>3) & 63;
        int cl   = lane & 31, half = lane >> 5;
        int kk   = t >> 9;           // tile*8+ks
        int ks   = kk & 7, tile = kk >> 3;
        int k = ks*16 + half*8 + j;
        int n = tile*32 + cl;
        W2B[t] = __float2bfloat16(W2[(size_t)k*1152 + n]);
    } else if (b < 752){
        int t = (b-576)*256 + threadIdx.x;
        if (t < 4*18*512){
            int j = t & 7;
            int lane = (t>>3) & 63;
            int cl = lane & 31, half = lane >> 5;
            int kk = t >> 9;                 // bb*18+ks
            int ks = kk % 18, bb = kk / 18;
            int k = ks*16 + half*8 + j;
            int c = bb*32 + cl;
            gW1B[t] = __float2bfloat16(k < 273 ? gW1[(size_t)k*128 + c] : 0.f);
        } else if (t < 4*18*512 + 4*4*512){
            int t2 = t - 4*18*512;
            int j = t2 & 7;
            int lane = (t2>>3) & 63;
            int cl = lane & 31, half = lane >> 5;
            int kk = t2 >> 9;                // bb*4+ks
            int ks = kk & 3, bb = kk >> 2;
            int k = ks*16 + half*8 + j;
            int c = bb*32 + cl;
            vwW1B[t2] = __float2bfloat16(k < 49 ? vwW1[(size_t)k*128 + c] : 0.f);
        }
    } else {
        // scales: one block per ef-row j, first 128 threads active
        __shared__ float s_e[32];
        __shared__ float s_s[128];
        const int j = b - 752, h = threadIdx.x;
        if (h >= 128) return;
        if (h < 32) s_e[h] = e_feat[j*32+h];
        __syncthreads();
        float a = eb1[h];
        #pragma unroll
        for (int k=0;k<32;k++) a += s_e[k]*eW1[k*128+h];
        s_s[h] = siluf(a);
        __syncthreads();
        if (h < 24){
            float acc = eb2[h];
            #pragma unroll 16
            for (int kk=0;kk<128;kk++) acc += s_s[kk]*eW2[kk*24+h];
            if (h < 16) sfull[j*40+h] = acc;
            else {
                int base = 16 + (h-16)*3;
                sfull[j*40+base+0] = acc;
                sfull[j*40+base+1] = acc;
                sfull[j*40+base+2] = acc;
            }
        }
    }
}

// ---------------- fused edge kernel: prep + W2 GEMM + contraction ----------------
// R10-verified (312us): VGPR 52, no scratch. af read from s_hid per tile; w101
// i3-outermost recompute; two-half ginf staging; (256,4). DO NOT add LDS-atomic
// accumulation in the tile loop (R8: 3x slower) or register dbuf (R1: regalloc kill).
__global__ __launch_bounds__(256, 4) void k_edge_fused(
    const float* __restrict__ h_flat, const float* __restrict__ h_full,
    const int* __restrict__ z,
    const int* __restrict__ att_src, const int* __restrict__ att_dst,
    const float* __restrict__ att_dist, const float* __restrict__ att_vec,
    const float* __restrict__ z_emb_W,
    const __hip_bfloat16* __restrict__ vwW1B, const float* __restrict__ vw_b1,
    const __hip_bfloat16* __restrict__ gW1B, const float* __restrict__ gb1,
    const float* __restrict__ gW2, const float* __restrict__ gb2,
    const __hip_bfloat16* __restrict__ W2B, const float* __restrict__ b2,
    float* __restrict__ ve_out)
{
    // persistent
    __shared__ uint4 s_hid4[512];         // 8192 B: hid bf16, fragment order
    __shared__ float s_rbf[EPA][16];
    __shared__ float s_sh1[EPA][3];
    __shared__ float s_d[EPA], s_env[EPA], s_self[EPA], s_gsum[EPA], s_coef[EPA];
    __shared__ int   s_src[EPA], s_dst[EPA];
    __shared__ float s_ve[EPA][40];
    __shared__ float s_p[EPA][8];
    // phase union: {ginf_half 576 + winf 256 uint4} / {sT 32x36, vT 48x36, t1T 16x36 f32}
    __shared__ uint4 s_uB[864];           // 13824 B

    uint4* s_ginf = s_uB;                 // [576]  (kc half-window)
    uint4* s_winf = s_uB + 576;           // [256]
    float* s_sT   = (float*)s_uB;         // [32*36]
    float* s_vT   = ((float*)s_uB) + 1152;// [48*36]
    float* s_t1T  = ((float*)s_uB) + 2880;// [16*36]
    __hip_bfloat16* s_hid = (__hip_bfloat16*)s_hid4;

    const int tid = threadIdx.x;
    const int e0  = blockIdx.x * EPA;
    const int lane = tid & 63, cl = lane & 31, half = lane >> 5;
    const int wave = tid >> 6;

    // ---- S0: per-edge scalars ----
    if (tid < EPA){
        int e  = e0 + tid;
        int sr = att_src[e], ds = att_dst[e];
        s_src[tid] = sr; s_dst[tid] = ds;
        float d = att_dist[e];
        s_d[tid] = d;
        float isf = (sr == ds) ? 1.f : 0.f;
        s_self[tid] = isf;
        float dc = fmaxf(d, 1e-8f);
        float ux = att_vec[e*3+0]/dc, uy = att_vec[e*3+1]/dc, uz = att_vec[e*3+2]/dc;
        float m = (isf > 0.f) ? 0.f : 1.7320508075688772f;
        s_sh1[tid][0] = m*uy; s_sh1[tid][1] = m*uz; s_sh1[tid][2] = m*ux;
        s_env[tid] = (d < 5.0f) ? 0.5f*(__cosf(0.6283185307179586f*d)+1.f) : 0.f;
        s_gsum[tid] = gb2[0];
    }
    __syncthreads();

    // ---- S1: rbf ----
    #pragma unroll
    for (int r=0;r<2;r++){
        int t = r*256 + tid; int e = t>>4, jj = t&15;
        float x = (s_d[e] - (float)jj*(1.f/3.f)) * 3.f;
        s_rbf[e][jj] = __expf(-0.5f*x*x);
    }
    __syncthreads();

    // ---- S2a: winf + ginf half A (kc 0..17) ----
    {   // winf: [zemb(32), isf(1), rbf(16), pad->64]
        int m = tid & 31, kc = tid >> 5;
        float v[8];
        if (kc < 4){
            const float* zr = z_emb_W + (size_t)z[s_dst[m]]*32 + kc*8;
            float4 a = *(const float4*)(zr);
            float4 b = *(const float4*)(zr+4);
            v[0]=a.x; v[1]=a.y; v[2]=a.z; v[3]=a.w;
            v[4]=b.x; v[5]=b.y; v[6]=b.z; v[7]=b.w;
        } else if (kc == 4){
            v[0] = s_self[m];
            #pragma unroll
            for (int j=0;j<7;j++) v[1+j] = s_rbf[m][j];
        } else if (kc == 5){
            #pragma unroll
            for (int j=0;j<8;j++) v[j] = s_rbf[m][7+j];
        } else if (kc == 6){
            v[0] = s_rbf[m][15];
            #pragma unroll
            for (int j=1;j<8;j++) v[j] = 0.f;
        } else {
            #pragma unroll
            for (int j=0;j<8;j++) v[j] = 0.f;
        }
        s_winf[kc*32 + m] = pack8(v);
    }
    for (int q = tid; q < 576; q += 256){  // kc 0..15: h_src; 16,17: h_dst chunks 0,1
        int m = q & 31, kc = q >> 5;
        int node = (kc < 16) ? s_src[m] : s_dst[m];
        int koff = (kc & 15)*8;
        const float* hp = h_flat + (size_t)node*128 + koff;
        float4 a = *(const float4*)(hp);
        float4 b = *(const float4*)(hp+4);
        float v[8] = {a.x,a.y,a.z,a.w,b.x,b.y,b.z,b.w};
        s_ginf[kc*32 + m] = pack8(v);
    }
    __syncthreads();

    // ---- S3a: vw GEMM (K=64) -> s_hid ; gate GEMM ks 0..8 ----
    const int c = wave*32 + cl;
    {
        f32x16 acc;
        float bias = vw_b1[c];
        #pragma unroll
        for (int i=0;i<16;i++) acc[i] = bias;
        #pragma unroll
        for (int ks=0;ks<4;ks++){
            frag8 afr = *((const frag8*)&s_winf[(ks*2+half)*32 + cl]);
            frag8 bfr = *(const frag8*)(vwW1B + ((size_t)(wave*4+ks)*64 + lane)*8);
            acc = __builtin_amdgcn_mfma_f32_32x32x16_bf16(afr, bfr, acc, 0, 0, 0);
        }
        __hip_bfloat16* hb = s_hid + (c>>4)*512 + ((c>>3)&1)*256 + (c&7);
        #pragma unroll
        for (int r=0;r<16;r++){
            int e = 4*half + (r&3) + 8*(r>>2);
            hb[e*8] = __float2bfloat16(siluf(acc[r]));
        }
    }
    f32x16 gacc;
    {
        float bias = gb1[c];
        #pragma unroll
        for (int i=0;i<16;i++) gacc[i] = bias;
        #pragma unroll
        for (int ks=0;ks<9;ks++){          // kc 0..17
            frag8 afr = *((const frag8*)&s_ginf[(ks*2+half)*32 + cl]);
            frag8 bfr = *(const frag8*)(gW1B + ((size_t)(wave*18+ks)*64 + lane)*8);
            gacc = __builtin_amdgcn_mfma_f32_32x32x16_bf16(afr, bfr, gacc, 0, 0, 0);
        }
    }
    __syncthreads();

    // ---- S2b: ginf half B (kc 18..35) ----
    for (int q = tid; q < 576; q += 256){
        int m = q & 31, kc2 = q >> 5;      // row kc2 <-> kc = kc2+18
        int kc = kc2 + 18;
        float v[8];
        if (kc < 32){                      // h_dst chunks 2..15
            int koff = (kc & 15)*8;
            const float* hp = h_flat + (size_t)s_dst[m]*128 + koff;
            float4 a = *(const float4*)(hp);
            float4 b = *(const float4*)(hp+4);
            v[0]=a.x; v[1]=a.y; v[2]=a.z; v[3]=a.w;
            v[4]=b.x; v[5]=b.y; v[6]=b.z; v[7]=b.w;
        } else if (kc == 32){
            #pragma unroll
            for (int j=0;j<8;j++) v[j] = s_rbf[m][j];
        } else if (kc == 33){
            #pragma unroll
            for (int j=0;j<8;j++) v[j] = s_rbf[m][8+j];
        } else if (kc == 34){
            v[0] = s_self[m];
            #pragma unroll
            for (int j=1;j<8;j++) v[j] = 0.f;
        } else {
            #pragma unroll
            for (int j=0;j<8;j++) v[j] = 0.f;
        }
        s_ginf[kc2*32 + m] = pack8(v);
    }
    __syncthreads();

    // ---- S3b: gate GEMM ks 9..17 + reduce ----
    {
        #pragma unroll
        for (int ks=9;ks<18;ks++){         // kc 18..35 -> row kc-18
            frag8 afr = *((const frag8*)&s_ginf[((ks*2+half)-18)*32 + cl]);
            frag8 bfr = *(const frag8*)(gW1B + ((size_t)(wave*18+ks)*64 + lane)*8);
            gacc = __builtin_amdgcn_mfma_f32_32x32x16_bf16(afr, bfr, gacc, 0, 0, 0);
        }
        float w2 = gW2[c];
        #pragma unroll
        for (int r=0;r<16;r++){
            float p = siluf(gacc[r]) * w2;
            p += __shfl_down(p, 16, 32);
            p += __shfl_down(p,  8, 32);
            p += __shfl_down(p,  4, 32);
            p += __shfl_down(p,  2, 32);
            p += __shfl_down(p,  1, 32);
            if (cl == 0){
                int e = 4*half + (r&3) + 8*(r>>2);
                atomicAdd(&s_gsum[e], p);
            }
        }
    }
    __syncthreads();   // hid + gsum ready; s_uB free

    // ---- S4: coeff; build sT/vT (union reuse); zero accumulators ----
    if (tid < EPA){
        float gate = 1.f/(1.f+__expf(-s_gsum[tid]));
        s_coef[tid] = s_env[tid]*gate;
    }
    #pragma unroll
    for (int r=0;r<4;r++){
        int t = r*256+tid; int u = t&31, e = t>>5;
        s_sT[u*36+e] = h_full[(size_t)s_dst[e]*80 + u];
    }
    #pragma unroll
    for (int r=0;r<6;r++){
        int t = r*256+tid; int q = t%48, e = t/48;
        s_vT[q*36+e] = h_full[(size_t)s_dst[e]*80 + 32 + q];
    }
    for (int t=tid; t<EPA*48; t+=256){
        int e = t/48, k = t%48;
        if (k < 40) s_ve[e][k] = 0.f; else s_p[e][k-40] = 0.f;
    }
    __syncthreads();

    // ---- S5: t1T from vT ----
    #pragma unroll
    for (int r=0;r<2;r++){
        int t = r*256+tid; int u = t>>5, e = t&31;
        s_t1T[u*36+e] = s_vT[(u*3+0)*36+e]*s_sh1[e][0]
                      + s_vT[(u*3+1)*36+e]*s_sh1[e][1]
                      + s_vT[(u*3+2)*36+e]*s_sh1[e][2];
    }
    __syncthreads();

    // ---- S6: W2 tile GEMMs + register contraction; af read from LDS per tile ----
    const int eoff = 4*half;
    const float RSQ3 = 0.5773502691896258f;
    const int  Tmain    = wave*8;
    const bool hasExtra = (wave >= 2);
    const int  Textra   = (wave==2) ? 32 : 34;
    const frag8* ap = (const frag8*)s_hid + half*32 + cl;   // + ks*64 per step

    auto mfma_tile = [&](int T)->f32x16{
        float bias = b2[T*32 + cl];
        f32x16 acc;
        #pragma unroll
        for (int q=0;q<16;q++) acc[q] = bias;
        const frag8* wb = (const frag8*)(W2B + (size_t)T*4096 + lane*8);
        #pragma unroll
        for (int ks=0;ks<8;ks++){
            frag8 bfr = wb[ks*64];
            frag8 afr = ap[ks*64];
            acc = __builtin_amdgcn_mfma_f32_32x32x16_bf16(afr, bfr, acc, 0, 0, 0);
        }
        return acc;
    };

    {
        float racc[16];
        #pragma unroll
        for (int r=0;r<16;r++) racc[r] = 0.f;
        #pragma unroll 1
        for (int i=0; i<8; ++i){
            int T = Tmain + i;
            f32x16 acc = mfma_tile(T);
            const float* wb;
            if (wave < 2)        wb = &s_sT [(2*T+(cl>>4))*36 + eoff];
            else if (wave == 2)  wb = &s_t1T[(2*i+(cl>>4))*36 + eoff];
            else                 wb = &s_sT [(4*i+(cl>>3))*36 + eoff];
            #pragma unroll
            for (int g=0; g<4; g++){
                float4 w4 = *(const float4*)(wb + 8*g);
                racc[4*g+0] += acc[4*g+0]*w4.x;
                racc[4*g+1] += acc[4*g+1]*w4.y;
                racc[4*g+2] += acc[4*g+2]*w4.z;
                racc[4*g+3] += acc[4*g+3]*w4.w;
            }
        }
        if (wave < 2){
            int v = cl & 15;
            #pragma unroll
            for (int r=0;r<16;r++){
                int e = eoff + (r&3) + 8*(r>>2);
                atomicAdd(&s_ve[e][v], racc[r]);
            }
        } else if (wave == 2){
            int v = cl & 15;
            #pragma unroll
            for (int r=0;r<16;r++){
                int e = eoff + (r&3) + 8*(r>>2);
                atomicAdd(&s_ve[e][v], racc[r]*RSQ3);
            }
        } else {
            int v = cl & 7;
            #pragma unroll
            for (int r=0;r<16;r++){
                int e = eoff + (r&3) + 8*(r>>2);
                atomicAdd(&s_p[e][v], racc[r]);
            }
        }
    }

    // w101 extra phase: i3 outermost, MFMAs recomputed per i3 (no r3 array)
    if (hasExtra){
        const int t0 = (wave==2) ? 0 : 2;
        #pragma unroll 1
        for (int i3=0;i3<3;i3++){
            float racc[16];
            #pragma unroll
            for (int r=0;r<16;r++) racc[r] = 0.f;
            #pragma unroll 1
            for (int tt=0; tt<2; ++tt){
                f32x16 acc = mfma_tile(Textra + tt);
                int u = 4*(t0+tt) + (cl>>3);
                const float* vb = &s_vT[(u*3+i3)*36 + eoff];
                #pragma unroll
                for (int g=0; g<4; g++){
                    float4 w4 = *(const float4*)(vb + 8*g);
                    racc[4*g+0] += acc[4*g+0]*w4.x;
                    racc[4*g+1] += acc[4*g+1]*w4.y;
                    racc[4*g+2] += acc[4*g+2]*w4.z;
                    racc[4*g+3] += acc[4*g+3]*w4.w;
                }
            }
            int v = cl & 7;
            #pragma unroll
            for (int r=0;r<16;r++){
                int e = eoff + (r&3) + 8*(r>>2);
                atomicAdd(&s_ve[e][16+v*3+i3], racc[r]);
            }
        }
    }
    __syncthreads();

    // ---- S7: flush (plain coalesced stores, linear layout) ----
    float* veb = ve_out + (size_t)e0*40;
    const float RFAN = 0.14433756729740643f; // 1/sqrt(48)
    #pragma unroll
    for (int r=0;r<5;r++){
        int t = r*256+tid; int e = t/40, s = t%40;
        float val;
        if (s < 16) val = s_ve[e][s];
        else {
            int v = (s-16)/3, i3 = (s-16)%3;
            val = s_p[e][v]*s_sh1[e][i3] + s_ve[e][s];
        }
        veb[t] = val * RFAN * s_coef[e];
    }
}

// ---------------- K2: gather + output MLP, 2 blocks per node (32 envs each) ----
__global__ __launch_bounds__(256) void k_out(
    const float* __restrict__ ve, const int* __restrict__ off, const int* __restrict__ elist,
    const float* __restrict__ sfull,
    const float* __restrict__ W1, const float* __restrict__ b1,
    const float* __restrict__ W2, const float* __restrict__ b2,
    const float* __restrict__ W3, const float* __restrict__ b3,
    float* __restrict__ out)
{
    __shared__ float s_part[6][40];
    __shared__ float s_irr[40];
    __shared__ float s_inv[32][24];
    __shared__ float s_x[32][128];

    const int tid = threadIdx.x;
    const int n   = blockIdx.x >> 1;
    const int p   = blockIdx.x & 1;       // env half: j in [p*32, p*32+32)

    // gather (full 40-vector for node n; duplicated across the two halves)
    {
        const int o0 = off[n], o1 = off[n+1];
        int c = tid/40, s = tid - c*40;
        if (c < 6){
            float acc = 0.f;
            for (int i = o0 + c; i < o1; i += 6){
                int e = elist[i];
                acc += ve[(size_t)e*40 + s];
            }
            s_part[c][s] = acc;
        }
    }
    __syncthreads();
    if (tid < 40){
        s_irr[tid] = s_part[0][tid]+s_part[1][tid]+s_part[2][tid]
                   + s_part[3][tid]+s_part[4][tid]+s_part[5][tid];
    }
    __syncthreads();

    // invariants for this half's 32 envs
    #pragma unroll
    for (int r=0;r<3;r++){
        int t = r*256+tid; int jl = t/24, c = t%24;
        int j = p*32 + jl;
        float v;
        if (c < 16) v = s_irr[c]*sfull[j*40+c];
        else {
            int base = 16 + (c-16)*3;
            float ss = 1e-12f;
            #pragma unroll
            for (int i=0;i<3;i++){ float x = s_irr[base+i]*sfull[j*40+base+i]; ss += x*x; }
            v = sqrtf(ss);
        }
        s_inv[jl][c] = v;
    }
    __syncthreads();

    const int h4 = (tid & 31)*4, jg = tid >> 5;
    float acc[4][4];

    // L1: K=24
    #pragma unroll
    for (int jj=0;jj<4;jj++)
        #pragma unroll
        for (int hh=0;hh<4;hh++) acc[jj][hh] = b1[h4+hh];
    #pragma unroll
    for (int k=0;k<24;k+=4){
        float4 w0 = *(const float4*)&W1[(k+0)*128+h4];
        float4 w1 = *(const float4*)&W1[(k+1)*128+h4];
        float4 w2 = *(const float4*)&W1[(k+2)*128+h4];
        float4 w3 = *(const float4*)&W1[(k+3)*128+h4];
        #pragma unroll
        for (int jj=0;jj<4;jj++){
            float4 xv = *(const float4*)&s_inv[jg*4+jj][k];
            acc[jj][0] += xv.x*w0.x + xv.y*w1.x + xv.z*w2.x + xv.w*w3.x;
            acc[jj][1] += xv.x*w0.y + xv.y*w1.y + xv.z*w2.y + xv.w*w3.y;
            acc[jj][2] += xv.x*w0.z + xv.y*w1.z + xv.z*w2.z + xv.w*w3.z;
            acc[jj][3] += xv.x*w0.w + xv.y*w1.w + xv.z*w2.w + xv.w*w3.w;
        }
    }
    #pragma unroll
    for (int jj=0;jj<4;jj++)
        *(float4*)&s_x[jg*4+jj][h4] = make_float4(siluf(acc[jj][0]), siluf(acc[jj][1]),
                                                  siluf(acc[jj][2]), siluf(acc[jj][3]));
    __syncthreads();

    // L2: K=128
    #pragma unroll
    for (int jj=0;jj<4;jj++)
        #pragma unroll
        for (int hh=0;hh<4;hh++) acc[jj][hh] = b2[h4+hh];
    for (int k=0;k<128;k+=4){
        float4 w0 = *(const float4*)&W2[(k+0)*128+h4];
        float4 w1 = *(const float4*)&W2[(k+1)*128+h4];
        float4 w2 = *(const float4*)&W2[(k+2)*128+h4];
        float4 w3 = *(const float4*)&W2[(k+3)*128+h4];
        #pragma unroll
        for (int jj=0;jj<4;jj++){
            float4 xv = *(const float4*)&s_x[jg*4+jj][k];
            acc[jj][0] += xv.x*w0.x + xv.y*w1.x + xv.z*w2.x + xv.w*w3.x;
            acc[jj][1] += xv.x*w0.y + xv.y*w1.y + xv.z*w2.y + xv.w*w3.y;
            acc[jj][2] += xv.x*w0.z + xv.y*w1.z + xv.z*w2.z + xv.w*w3.z;
            acc[jj][3] += xv.x*w0.w + xv.y*w1.w + xv.z*w2.w + xv.w*w3.w;
        }
    }
    __syncthreads();
    #pragma unroll
    for (int jj=0;jj<4;jj++)
        *(float4*)&s_x[jg*4+jj][h4] = make_float4(siluf(acc[jj][0]), siluf(acc[jj][1]),
                                                  siluf(acc[jj][2]), siluf(acc[jj][3]));
    __syncthreads();

    // L3: K=128
    #pragma unroll
    for (int jj=0;jj<4;jj++)
        #pragma unroll
        for (int hh=0;hh<4;hh++) acc[jj][hh] = b3[h4+hh];
    for (int k=0;k<128;k+=4){
        float4 w0 = *(const float4*)&W3[(k+0)*128+h4];
        float4 w1 = *(const float4*)&W3[(k+1)*128+h4];
        float4 w2 = *(const float4*)&W3[(k+2)*128+h4];
        float4 w3 = *(const float4*)&W3[(k+3)*128+h4];
        #pragma unroll
        for (int jj=0;jj<4;jj++){
            float4 xv = *(const float4*)&s_x[jg*4+jj][k];
            acc[jj][0] += xv.x*w0.x + xv.y*w1.x + xv.z*w2.x + xv.w*w3.x;
            acc[jj][1] += xv.x*w0.y + xv.y*w1.y + xv.z*w2.y + xv.w*w3.y;
            acc[jj][2] += xv.x*w0.z + xv.y*w1.z + xv.z*w2.z + xv.w*w3.z;
            acc[jj][3] += xv.x*w0.w + xv.y*w1.w + xv.z*w2.w + xv.w*w3.w;
        }
    }
    #pragma unroll
    for (int jj=0;jj<4;jj++){
        int j = p*32 + jg*4+jj;
        *(float4*)&out[((size_t)n*64 + j)*128 + h4] =
            make_float4(acc[jj][0], acc[jj][1], acc[jj][2], acc[jj][3]);
    }
}

// ---------------- launch ----------------
extern "C" void kernel_launch(void* const* d_in, const int* in_sizes, int n_in,
                              void* d_out, int out_size, void* d_ws, size_t ws_size,
                              hipStream_t stream)
{
    const float* h        = (const float*)d_in[0];
    const float* h_full   = (const float*)d_in[1];
    const float* e_feat   = (const float*)d_in[2];
    const float* att_dist = (const float*)d_in[3];
    const float* att_vec  = (const float*)d_in[4];
    const int*   z        = (const int*)d_in[5];
    const int* att_src    = (const int*)d_in[7];
    const int* att_dst    = (const int*)d_in[8];
    const float* z_emb_W  = (const float*)d_in[9];
    const float* vw_W1    = (const float*)d_in[10];
    const float* vw_b1    = (const float*)d_in[11];
    const float* vw_W2    = (const float*)d_in[12];
    const float* vw_b2    = (const float*)d_in[13];
    const float* gW1      = (const float*)d_in[14];
    const float* gb1      = (const float*)d_in[15];
    const float* gW2      = (const float*)d_in[16];
    const float* gb2      = (const float*)d_in[17];
    const float* emW1     = (const float*)d_in[18];
    const float* emb1     = (const float*)d_in[19];
    const float* emW2     = (const float*)d_in[20];
    const float* emb2     = (const float*)d_in[21];
    const float* oW1      = (const float*)d_in[22];
    const float* ob1      = (const float*)d_in[23];
    const float* oW2      = (const float*)d_in[24];
    const float* ob2      = (const float*)d_in[25];
    const float* oW3      = (const float*)d_in[26];
    const float* ob3      = (const float*)d_in[27];
    float* out = (float*)d_out;

    char* ws = (char*)d_ws;
    float* ve    = (float*)ws;                                   // EDG*40*4 = 20.97 MB
    float* sfull = ve + (size_t)EDG*40;                          // 10 KB
    __hip_bfloat16* W2B   = (__hip_bfloat16*)(sfull + (size_t)NEF*40); // 294,912 B
    __hip_bfloat16* gW1B  = W2B  + (size_t)36*8*512;             // 73,728 B
    __hip_bfloat16* vwW1B = gW1B + (size_t)4*18*512;             // 16,384 B
    int* cnt   = (int*)(vwW1B + (size_t)4*4*512);                // 8 KB
    int* off   = cnt + 2048;
    int* cur   = off + 2049;
    int* elist = cur + 2048;                                     // 512 KB

    hipMemsetAsync(cnt, 0, 2048*sizeof(int), stream);
    k_hist    <<<EDG/256, 256, 0, stream>>>(att_src, cnt);
    k_scan    <<<1, 1024, 0, stream>>>(cnt, off, cur);
    k_scatter <<<EDG/256, 256, 0, stream>>>(att_src, cur, elist);
    k_prep    <<<816, 256, 0, stream>>>(vw_W2, W2B, gW1, vw_W1, gW1B, vwW1B,
                                        emW1, emb1, emW2, emb2, e_feat, sfull);
    k_edge_fused<<<EDG/EPA, 256, 0, stream>>>(h, h_full, z, att_src, att_dst,
        att_dist, att_vec, z_emb_W, vwW1B, vw_b1, gW1B, gb1, gW2, gb2,
        W2B, vw_b2, ve);
    k_out<<<FLAT*2, 256, 0, stream>>>(ve, off, elist, sfull,
        oW1, ob1, oW2, ob2, oW3, ob3, out);
}

// Round 12
// 603.880 us; speedup vs baseline: 1.0585x; 1.0585x over previous
//
#include <hip/hip_runtime.h>
#include <hip/hip_bf16.h>

#define FLAT   2048
#define EDG    131072
#define NEF    64
#define EPA    32

typedef short  frag8  __attribute__((ext_vector_type(8)));   // 8 bf16 = 4 VGPRs
typedef float  f32x16 __attribute__((ext_vector_type(16)));  // MFMA 32x32 acc

__device__ __forceinline__ float siluf(float x){ return x / (1.f + __expf(-x)); }

__device__ __forceinline__ uint4 pack8(const float v[8]){
    union { uint4 u; __hip_bfloat16 h[8]; } r;
    #pragma unroll
    for (int i=0;i<8;i++) r.h[i] = __float2bfloat16(v[i]);
    return r.u;
}

// ---------------- tiny helpers ----------------
__global__ void k_hist(const int* __restrict__ src, int* __restrict__ cnt){
    int e = blockIdx.x*256 + threadIdx.x;
    if (e < EDG) atomicAdd(&cnt[src[e]], 1);
}

__global__ __launch_bounds__(1024) void k_scan(const int* __restrict__ cnt,
                                               int* __restrict__ off, int* __restrict__ cur){
    __shared__ int s[2048];
    const int tid = threadIdx.x;
    s[tid]      = cnt[tid];
    s[tid+1024] = cnt[tid+1024];
    __syncthreads();
    for (int d=1; d<2048; d<<=1){
        int a = (tid      >= d) ? s[tid      -d] : 0;
        int b = (tid+1024 >= d) ? s[tid+1024 -d] : 0;
        __syncthreads();
        s[tid]      += a;
        s[tid+1024] += b;
        __syncthreads();
    }
    int e0 = (tid==0) ? 0 : s[tid-1];
    int e1 = s[tid+1023];
    off[tid]      = e0;  cur[tid]      = e0;
    off[tid+1024] = e1;  cur[tid+1024] = e1;
    if (tid==0) off[2048] = s[2047];
}

// inverse permutation: slot[e] = CSR position of edge e (rows of ve become
// src-sorted so k_out's gather is contiguous)
__global__ void k_scatter(const int* __restrict__ src, int* __restrict__ cur,
                          int* __restrict__ slot){
    int e = blockIdx.x*256 + threadIdx.x;
    if (e < EDG){
        int p = atomicAdd(&cur[src[e]], 1);
        slot[e] = p;
    }
}

// vw_W2 (128x1152 f32, k-major) -> W2B fragment-major bf16
__global__ void k_cvtW2(const float* __restrict__ W2, __hip_bfloat16* __restrict__ W2B){
    int t = blockIdx.x*256 + threadIdx.x;
    if (t >= 36*8*512) return;
    int j    = t & 7;
    int lane = (t>>3) & 63;
    int cl   = lane & 31, half = lane >> 5;
    int kk   = t >> 9;           // tile*8+ks
    int ks   = kk & 7, tile = kk >> 3;
    int k = ks*16 + half*8 + j;
    int n = tile*32 + cl;
    W2B[t] = __float2bfloat16(W2[(size_t)k*1152 + n]);
}

// gW1 (273x128) / vw_W1 (49x128) -> frag-major bf16 (zero-padded K)
__global__ void k_cvtW1s(const float* __restrict__ gW1, const float* __restrict__ vwW1,
                         __hip_bfloat16* __restrict__ gW1B, __hip_bfloat16* __restrict__ vwW1B){
    int t = blockIdx.x*256 + threadIdx.x;
    if (t < 4*18*512){
        int j = t & 7;
        int lane = (t>>3) & 63;
        int cl = lane & 31, half = lane >> 5;
        int kk = t >> 9;                 // b*18+ks
        int ks = kk % 18, b = kk / 18;
        int k = ks*16 + half*8 + j;
        int c = b*32 + cl;
        gW1B[t] = __float2bfloat16(k < 273 ? gW1[(size_t)k*128 + c] : 0.f);
    } else if (t < 4*18*512 + 4*4*512){
        int t2 = t - 4*18*512;
        int j = t2 & 7;
        int lane = (t2>>3) & 63;
        int cl = lane & 31, half = lane >> 5;
        int kk = t2 >> 9;                // b*4+ks
        int ks = kk & 3, b = kk >> 2;
        int k = ks*16 + half*8 + j;
        int c = b*32 + cl;
        vwW1B[t2] = __float2bfloat16(k < 49 ? vwW1[(size_t)k*128 + c] : 0.f);
    }
}

// scales, parallel: one block per ef-row j
__global__ __launch_bounds__(128) void k_scales(const float* __restrict__ e_feat,
                         const float* __restrict__ W1, const float* __restrict__ b1,
                         const float* __restrict__ W2, const float* __restrict__ b2,
                         float* __restrict__ sfull){
    __shared__ float s_e[32];
    __shared__ float s_s[128];
    const int j = blockIdx.x, h = threadIdx.x;
    if (h < 32) s_e[h] = e_feat[j*32+h];
    __syncthreads();
    float a = b1[h];
    #pragma unroll
    for (int k=0;k<32;k++) a += s_e[k]*W1[k*128+h];
    s_s[h] = siluf(a);
    __syncthreads();
    if (h < 24){
        float acc = b2[h];
        #pragma unroll 16
        for (int kk=0;kk<128;kk++) acc += s_s[kk]*W2[kk*24+h];
        if (h < 16) sfull[j*40+h] = acc;
        else {
            int base = 16 + (h-16)*3;
            sfull[j*40+base+0] = acc;
            sfull[j*40+base+1] = acc;
            sfull[j*40+base+2] = acc;
        }
    }
}

// ---------------- fused edge kernel: prep + W2 GEMM + contraction ----------------
// R10-verified body (312us). ONE change: flush writes each edge row at its CSR
// slot (src-sorted ve) so k_out's gather is contiguous. DO NOT add LDS-atomic
// accumulation in the tile loop (R8: 3x slower) or register dbuf (R1: regalloc kill).
__global__ __launch_bounds__(256, 4) void k_edge_fused(
    const float* __restrict__ h_flat, const float* __restrict__ h_full,
    const int* __restrict__ z,
    const int* __restrict__ att_src, const int* __restrict__ att_dst,
    const float* __restrict__ att_dist, const float* __restrict__ att_vec,
    const float* __restrict__ z_emb_W, const int* __restrict__ slot,
    const __hip_bfloat16* __restrict__ vwW1B, const float* __restrict__ vw_b1,
    const __hip_bfloat16* __restrict__ gW1B, const float* __restrict__ gb1,
    const float* __restrict__ gW2, const float* __restrict__ gb2,
    const __hip_bfloat16* __restrict__ W2B, const float* __restrict__ b2,
    float* __restrict__ ve_out)
{
    // persistent
    __shared__ uint4 s_hid4[512];         // 8192 B: hid bf16, fragment order
    __shared__ float s_rbf[EPA][16];
    __shared__ float s_sh1[EPA][3];
    __shared__ float s_d[EPA], s_env[EPA], s_self[EPA], s_gsum[EPA], s_coef[EPA];
    __shared__ int   s_src[EPA], s_dst[EPA], s_slot[EPA];
    __shared__ float s_ve[EPA][40];
    __shared__ float s_p[EPA][8];
    // phase union: {ginf_half 576 + winf 256 uint4} / {sT 32x36, vT 48x36, t1T 16x36 f32}
    __shared__ uint4 s_uB[864];           // 13824 B

    uint4* s_ginf = s_uB;                 // [576]  (kc half-window)
    uint4* s_winf = s_uB + 576;           // [256]
    float* s_sT   = (float*)s_uB;         // [32*36]
    float* s_vT   = ((float*)s_uB) + 1152;// [48*36]
    float* s_t1T  = ((float*)s_uB) + 2880;// [16*36]
    __hip_bfloat16* s_hid = (__hip_bfloat16*)s_hid4;

    const int tid = threadIdx.x;
    const int e0  = blockIdx.x * EPA;
    const int lane = tid & 63, cl = lane & 31, half = lane >> 5;
    const int wave = tid >> 6;

    // ---- S0: per-edge scalars ----
    if (tid < EPA){
        int e  = e0 + tid;
        int sr = att_src[e], ds = att_dst[e];
        s_src[tid] = sr; s_dst[tid] = ds;
        s_slot[tid] = slot[e];
        float d = att_dist[e];
        s_d[tid] = d;
        float isf = (sr == ds) ? 1.f : 0.f;
        s_self[tid] = isf;
        float dc = fmaxf(d, 1e-8f);
        float ux = att_vec[e*3+0]/dc, uy = att_vec[e*3+1]/dc, uz = att_vec[e*3+2]/dc;
        float m = (isf > 0.f) ? 0.f : 1.7320508075688772f;
        s_sh1[tid][0] = m*uy; s_sh1[tid][1] = m*uz; s_sh1[tid][2] = m*ux;
        s_env[tid] = (d < 5.0f) ? 0.5f*(__cosf(0.6283185307179586f*d)+1.f) : 0.f;
        s_gsum[tid] = gb2[0];
    }
    __syncthreads();

    // ---- S1: rbf ----
    #pragma unroll
    for (int r=0;r<2;r++){
        int t = r*256 + tid; int e = t>>4, jj = t&15;
        float x = (s_d[e] - (float)jj*(1.f/3.f)) * 3.f;
        s_rbf[e][jj] = __expf(-0.5f*x*x);
    }
    __syncthreads();

    // ---- S2a: winf + ginf half A (kc 0..17) ----
    {   // winf: [zemb(32), isf(1), rbf(16), pad->64]
        int m = tid & 31, kc = tid >> 5;
        float v[8];
        if (kc < 4){
            const float* zr = z_emb_W + (size_t)z[s_dst[m]]*32 + kc*8;
            float4 a = *(const float4*)(zr);
            float4 b = *(const float4*)(zr+4);
            v[0]=a.x; v[1]=a.y; v[2]=a.z; v[3]=a.w;
            v[4]=b.x; v[5]=b.y; v[6]=b.z; v[7]=b.w;
        } else if (kc == 4){
            v[0] = s_self[m];
            #pragma unroll
            for (int j=0;j<7;j++) v[1+j] = s_rbf[m][j];
        } else if (kc == 5){
            #pragma unroll
            for (int j=0;j<8;j++) v[j] = s_rbf[m][7+j];
        } else if (kc == 6){
            v[0] = s_rbf[m][15];
            #pragma unroll
            for (int j=1;j<8;j++) v[j] = 0.f;
        } else {
            #pragma unroll
            for (int j=0;j<8;j++) v[j] = 0.f;
        }
        s_winf[kc*32 + m] = pack8(v);
    }
    for (int q = tid; q < 576; q += 256){  // kc 0..15: h_src; 16,17: h_dst chunks 0,1
        int m = q & 31, kc = q >> 5;
        int node = (kc < 16) ? s_src[m] : s_dst[m];
        int koff = (kc & 15)*8;
        const float* hp = h_flat + (size_t)node*128 + koff;
        float4 a = *(const float4*)(hp);
        float4 b = *(const float4*)(hp+4);
        float v[8] = {a.x,a.y,a.z,a.w,b.x,b.y,b.z,b.w};
        s_ginf[kc*32 + m] = pack8(v);
    }
    __syncthreads();

    // ---- S3a: vw GEMM (K=64) -> s_hid ; gate GEMM ks 0..8 ----
    const int c = wave*32 + cl;
    {
        f32x16 acc;
        float bias = vw_b1[c];
        #pragma unroll
        for (int i=0;i<16;i++) acc[i] = bias;
        #pragma unroll
        for (int ks=0;ks<4;ks++){
            frag8 afr = *((const frag8*)&s_winf[(ks*2+half)*32 + cl]);
            frag8 bfr = *(const frag8*)(vwW1B + ((size_t)(wave*4+ks)*64 + lane)*8);
            acc = __builtin_amdgcn_mfma_f32_32x32x16_bf16(afr, bfr, acc, 0, 0, 0);
        }
        __hip_bfloat16* hb = s_hid + (c>>4)*512 + ((c>>3)&1)*256 + (c&7);
        #pragma unroll
        for (int r=0;r<16;r++){
            int e = 4*half + (r&3) + 8*(r>>2);
            hb[e*8] = __float2bfloat16(siluf(acc[r]));
        }
    }
    f32x16 gacc;
    {
        float bias = gb1[c];
        #pragma unroll
        for (int i=0;i<16;i++) gacc[i] = bias;
        #pragma unroll
        for (int ks=0;ks<9;ks++){          // kc 0..17
            frag8 afr = *((const frag8*)&s_ginf[(ks*2+half)*32 + cl]);
            frag8 bfr = *(const frag8*)(gW1B + ((size_t)(wave*18+ks)*64 + lane)*8);
            gacc = __builtin_amdgcn_mfma_f32_32x32x16_bf16(afr, bfr, gacc, 0, 0, 0);
        }
    }
    __syncthreads();

    // ---- S2b: ginf half B (kc 18..35) ----
    for (int q = tid; q < 576; q += 256){
        int m = q & 31, kc2 = q >> 5;      // row kc2 <-> kc = kc2+18
        int kc = kc2 + 18;
        float v[8];
        if (kc < 32){                      // h_dst chunks 2..15
            int koff = (kc & 15)*8;
            const float* hp = h_flat + (size_t)s_dst[m]*128 + koff;
            float4 a = *(const float4*)(hp);
            float4 b = *(const float4*)(hp+4);
            v[0]=a.x; v[1]=a.y; v[2]=a.z; v[3]=a.w;
            v[4]=b.x; v[5]=b.y; v[6]=b.z; v[7]=b.w;
        } else if (kc == 32){
            #pragma unroll
            for (int j=0;j<8;j++) v[j] = s_rbf[m][j];
        } else if (kc == 33){
            #pragma unroll
            for (int j=0;j<8;j++) v[j] = s_rbf[m][8+j];
        } else if (kc == 34){
            v[0] = s_self[m];
            #pragma unroll
            for (int j=1;j<8;j++) v[j] = 0.f;
        } else {
            #pragma unroll
            for (int j=0;j<8;j++) v[j] = 0.f;
        }
        s_ginf[kc2*32 + m] = pack8(v);
    }
    __syncthreads();

    // ---- S3b: gate GEMM ks 9..17 + reduce ----
    {
        #pragma unroll
        for (int ks=9;ks<18;ks++){         // kc 18..35 -> row kc-18
            frag8 afr = *((const frag8*)&s_ginf[((ks*2+half)-18)*32 + cl]);
            frag8 bfr = *(const frag8*)(gW1B + ((size_t)(wave*18+ks)*64 + lane)*8);
            gacc = __builtin_amdgcn_mfma_f32_32x32x16_bf16(afr, bfr, gacc, 0, 0, 0);
        }
        float w2 = gW2[c];
        #pragma unroll
        for (int r=0;r<16;r++){
            float p = siluf(gacc[r]) * w2;
            p += __shfl_down(p, 16, 32);
            p += __shfl_down(p,  8, 32);
            p += __shfl_down(p,  4, 32);
            p += __shfl_down(p,  2, 32);
            p += __shfl_down(p,  1, 32);
            if (cl == 0){
                int e = 4*half + (r&3) + 8*(r>>2);
                atomicAdd(&s_gsum[e], p);
            }
        }
    }
    __syncthreads();   // hid + gsum ready; s_uB free

    // ---- S4: coeff; build sT/vT (union reuse); zero accumulators ----
    if (tid < EPA){
        float gate = 1.f/(1.f+__expf(-s_gsum[tid]));
        s_coef[tid] = s_env[tid]*gate;
    }
    #pragma unroll
    for (int r=0;r<4;r++){
        int t = r*256+tid; int u = t&31, e = t>>5;
        s_sT[u*36+e] = h_full[(size_t)s_dst[e]*80 + u];
    }
    #pragma unroll
    for (int r=0;r<6;r++){
        int t = r*256+tid; int q = t%48, e = t/48;
        s_vT[q*36+e] = h_full[(size_t)s_dst[e]*80 + 32 + q];
    }
    for (int t=tid; t<EPA*48; t+=256){
        int e = t/48, k = t%48;
        if (k < 40) s_ve[e][k] = 0.f; else s_p[e][k-40] = 0.f;
    }
    __syncthreads();

    // ---- S5: t1T from vT ----
    #pragma unroll
    for (int r=0;r<2;r++){
        int t = r*256+tid; int u = t>>5, e = t&31;
        s_t1T[u*36+e] = s_vT[(u*3+0)*36+e]*s_sh1[e][0]
                      + s_vT[(u*3+1)*36+e]*s_sh1[e][1]
                      + s_vT[(u*3+2)*36+e]*s_sh1[e][2];
    }
    __syncthreads();

    // ---- S6: W2 tile GEMMs + register contraction; af read from LDS per tile ----
    const int eoff = 4*half;
    const float RSQ3 = 0.5773502691896258f;
    const int  Tmain    = wave*8;
    const bool hasExtra = (wave >= 2);
    const int  Textra   = (wave==2) ? 32 : 34;
    const frag8* ap = (const frag8*)s_hid + half*32 + cl;   // + ks*64 per step

    auto mfma_tile = [&](int T)->f32x16{
        float bias = b2[T*32 + cl];
        f32x16 acc;
        #pragma unroll
        for (int q=0;q<16;q++) acc[q] = bias;
        const frag8* wb = (const frag8*)(W2B + (size_t)T*4096 + lane*8);
        #pragma unroll
        for (int ks=0;ks<8;ks++){
            frag8 bfr = wb[ks*64];
            frag8 afr = ap[ks*64];
            acc = __builtin_amdgcn_mfma_f32_32x32x16_bf16(afr, bfr, acc, 0, 0, 0);
        }
        return acc;
    };

    {
        float racc[16];
        #pragma unroll
        for (int r=0;r<16;r++) racc[r] = 0.f;
        #pragma unroll 1
        for (int i=0; i<8; ++i){
            int T = Tmain + i;
            f32x16 acc = mfma_tile(T);
            const float* wb;
            if (wave < 2)        wb = &s_sT [(2*T+(cl>>4))*36 + eoff];
            else if (wave == 2)  wb = &s_t1T[(2*i+(cl>>4))*36 + eoff];
            else                 wb = &s_sT [(4*i+(cl>>3))*36 + eoff];
            #pragma unroll
            for (int g=0; g<4; g++){
                float4 w4 = *(const float4*)(wb + 8*g);
                racc[4*g+0] += acc[4*g+0]*w4.x;
                racc[4*g+1] += acc[4*g+1]*w4.y;
                racc[4*g+2] += acc[4*g+2]*w4.z;
                racc[4*g+3] += acc[4*g+3]*w4.w;
            }
        }
        if (wave < 2){
            int v = cl & 15;
            #pragma unroll
            for (int r=0;r<16;r++){
                int e = eoff + (r&3) + 8*(r>>2);
                atomicAdd(&s_ve[e][v], racc[r]);
            }
        } else if (wave == 2){
            int v = cl & 15;
            #pragma unroll
            for (int r=0;r<16;r++){
                int e = eoff + (r&3) + 8*(r>>2);
                atomicAdd(&s_ve[e][v], racc[r]*RSQ3);
            }
        } else {
            int v = cl & 7;
            #pragma unroll
            for (int r=0;r<16;r++){
                int e = eoff + (r&3) + 8*(r>>2);
                atomicAdd(&s_p[e][v], racc[r]);
            }
        }
    }

    // w101 extra phase: i3 outermost, MFMAs recomputed per i3 (no r3 array)
    if (hasExtra){
        const int t0 = (wave==2) ? 0 : 2;
        #pragma unroll 1
        for (int i3=0;i3<3;i3++){
            float racc[16];
            #pragma unroll
            for (int r=0;r<16;r++) racc[r] = 0.f;
            #pragma unroll 1
            for (int tt=0; tt<2; ++tt){
                f32x16 acc = mfma_tile(Textra + tt);
                int u = 4*(t0+tt) + (cl>>3);
                const float* vb = &s_vT[(u*3+i3)*36 + eoff];
                #pragma unroll
                for (int g=0; g<4; g++){
                    float4 w4 = *(const float4*)(vb + 8*g);
                    racc[4*g+0] += acc[4*g+0]*w4.x;
                    racc[4*g+1] += acc[4*g+1]*w4.y;
                    racc[4*g+2] += acc[4*g+2]*w4.z;
                    racc[4*g+3] += acc[4*g+3]*w4.w;
                }
            }
            int v = cl & 7;
            #pragma unroll
            for (int r=0;r<16;r++){
                int e = eoff + (r&3) + 8*(r>>2);
                atomicAdd(&s_ve[e][16+v*3+i3], racc[r]);
            }
        }
    }
    __syncthreads();

    // ---- S7: flush to CSR slot (src-sorted rows; scattered 160B row writes) ----
    const float RFAN = 0.14433756729740643f; // 1/sqrt(48)
    #pragma unroll
    for (int r=0;r<5;r++){
        int t = r*256+tid; int e = t/40, s = t%40;
        float val;
        if (s < 16) val = s_ve[e][s];
        else {
            int v = (s-16)/3, i3 = (s-16)%3;
            val = s_p[e][v]*s_sh1[e][i3] + s_ve[e][s];
        }
        ve_out[(size_t)s_slot[e]*40 + s] = val * RFAN * s_coef[e];
    }
}

// ---------------- K2: contiguous gather + output MLP (R4-verified MLP body) ----
__global__ __launch_bounds__(256) void k_out(
    const float* __restrict__ ve, const int* __restrict__ off,
    const float* __restrict__ sfull,
    const float* __restrict__ W1, const float* __restrict__ b1,
    const float* __restrict__ W2, const float* __restrict__ b2,
    const float* __restrict__ W3, const float* __restrict__ b3,
    float* __restrict__ out)
{
    __shared__ float s_part[6][40];
    __shared__ float s_irr[40];
    __shared__ float s_inv[64][24];
    __shared__ float s_x[64][128];

    const int tid = threadIdx.x;
    const int n   = blockIdx.x;

    // gather: rows [off[n], off[n+1]) are contiguous (src-sorted ve)
    {
        const int o0 = off[n], o1 = off[n+1];
        int c = tid/40, s = tid - c*40;
        if (c < 6){
            float acc = 0.f;
            for (int i = o0 + c; i < o1; i += 6)
                acc += ve[(size_t)i*40 + s];
            s_part[c][s] = acc;
        }
    }
    __syncthreads();
    if (tid < 40){
        s_irr[tid] = s_part[0][tid]+s_part[1][tid]+s_part[2][tid]
                   + s_part[3][tid]+s_part[4][tid]+s_part[5][tid];
    }
    __syncthreads();

    #pragma unroll
    for (int r=0;r<6;r++){
        int t = r*256+tid; int j = t/24, c = t%24;
        float v;
        if (c < 16) v = s_irr[c]*sfull[j*40+c];
        else {
            int base = 16 + (c-16)*3;
            float ss = 1e-12f;
            #pragma unroll
            for (int i=0;i<3;i++){ float x = s_irr[base+i]*sfull[j*40+base+i]; ss += x*x; }
            v = sqrtf(ss);
        }
        s_inv[j][c] = v;
    }
    __syncthreads();

    const int h4 = (tid & 31)*4, jg = tid >> 5;
    float acc[8][4];

    #pragma unroll
    for (int jj=0;jj<8;jj++)
        #pragma unroll
        for (int hh=0;hh<4;hh++) acc[jj][hh] = b1[h4+hh];
    #pragma unroll
    for (int k=0;k<24;k+=4){
        float4 w0 = *(const float4*)&W1[(k+0)*128+h4];
        float4 w1 = *(const float4*)&W1[(k+1)*128+h4];
        float4 w2 = *(const float4*)&W1[(k+2)*128+h4];
        float4 w3 = *(const float4*)&W1[(k+3)*128+h4];
        #pragma unroll
        for (int jj=0;jj<8;jj++){
            float4 xv = *(const float4*)&s_inv[jg*8+jj][k];
            acc[jj][0] += xv.x*w0.x + xv.y*w1.x + xv.z*w2.x + xv.w*w3.x;
            acc[jj][1] += xv.x*w0.y + xv.y*w1.y + xv.z*w2.y + xv.w*w3.y;
            acc[jj][2] += xv.x*w0.z + xv.y*w1.z + xv.z*w2.z + xv.w*w3.z;
            acc[jj][3] += xv.x*w0.w + xv.y*w1.w + xv.z*w2.w + xv.w*w3.w;
        }
    }
    #pragma unroll
    for (int jj=0;jj<8;jj++)
        *(float4*)&s_x[jg*8+jj][h4] = make_float4(siluf(acc[jj][0]), siluf(acc[jj][1]),
                                                  siluf(acc[jj][2]), siluf(acc[jj][3]));
    __syncthreads();

    #pragma unroll
    for (int jj=0;jj<8;jj++)
        #pragma unroll
        for (int hh=0;hh<4;hh++) acc[jj][hh] = b2[h4+hh];
    for (int k=0;k<128;k+=4){
        float4 w0 = *(const float4*)&W2[(k+0)*128+h4];
        float4 w1 = *(const float4*)&W2[(k+1)*128+h4];
        float4 w2 = *(const float4*)&W2[(k+2)*128+h4];
        float4 w3 = *(const float4*)&W2[(k+3)*128+h4];
        #pragma unroll
        for (int jj=0;jj<8;jj++){
            float4 xv = *(const float4*)&s_x[jg*8+jj][k];
            acc[jj][0] += xv.x*w0.x + xv.y*w1.x + xv.z*w2.x + xv.w*w3.x;
            acc[jj][1] += xv.x*w0.y + xv.y*w1.y + xv.z*w2.y + xv.w*w3.y;
            acc[jj][2] += xv.x*w0.z + xv.y*w1.z + xv.z*w2.z + xv.w*w3.z;
            acc[jj][3] += xv.x*w0.w + xv.y*w1.w + xv.z*w2.w + xv.w*w3.w;
        }
    }
    __syncthreads();
    #pragma unroll
    for (int jj=0;jj<8;jj++)
        *(float4*)&s_x[jg*8+jj][h4] = make_float4(siluf(acc[jj][0]), siluf(acc[jj][1]),
                                                  siluf(acc[jj][2]), siluf(acc[jj][3]));
    __syncthreads();

    #pragma unroll
    for (int jj=0;jj<8;jj++)
        #pragma unroll
        for (int hh=0;hh<4;hh++) acc[jj][hh] = b3[h4+hh];
    for (int k=0;k<128;k+=4){
        float4 w0 = *(const float4*)&W3[(k+0)*128+h4];
        float4 w1 = *(const float4*)&W3[(k+1)*128+h4];
        float4 w2 = *(const float4*)&W3[(k+2)*128+h4];
        float4 w3 = *(const float4*)&W3[(k+3)*128+h4];
        #pragma unroll
        for (int jj=0;jj<8;jj++){
            float4 xv = *(const float4*)&s_x[jg*8+jj][k];
            acc[jj][0] += xv.x*w0.x + xv.y*w1.x + xv.z*w2.x + xv.w*w3.x;
            acc[jj][1] += xv.x*w0.y + xv.y*w1.y + xv.z*w2.y + xv.w*w3.y;
            acc[jj][2] += xv.x*w0.z + xv.y*w1.z + xv.z*w2.z + xv.w*w3.z;
            acc[jj][3] += xv.x*w0.w + xv.y*w1.w + xv.z*w2.w + xv.w*w3.w;
        }
    }
    #pragma unroll
    for (int jj=0;jj<8;jj++){
        int j = jg*8+jj;
        *(float4*)&out[((size_t)n*64 + j)*128 + h4] =
            make_float4(acc[jj][0], acc[jj][1], acc[jj][2], acc[jj][3]);
    }
}

// ---------------- launch ----------------
extern "C" void kernel_launch(void* const* d_in, const int* in_sizes, int n_in,
                              void* d_out, int out_size, void* d_ws, size_t ws_size,
                              hipStream_t stream)
{
    const float* h        = (const float*)d_in[0];
    const float* h_full   = (const float*)d_in[1];
    const float* e_feat   = (const float*)d_in[2];
    const float* att_dist = (const float*)d_in[3];
    const float* att_vec  = (const float*)d_in[4];
    const int*   z        = (const int*)d_in[5];
    const int* att_src    = (const int*)d_in[7];
    const int* att_dst    = (const int*)d_in[8];
    const float* z_emb_W  = (const float*)d_in[9];
    const float* vw_W1    = (const float*)d_in[10];
    const float* vw_b1    = (const float*)d_in[11];
    const float* vw_W2    = (const float*)d_in[12];
    const float* vw_b2    = (const float*)d_in[13];
    const float* gW1      = (const float*)d_in[14];
    const float* gb1      = (const float*)d_in[15];
    const float* gW2      = (const float*)d_in[16];
    const float* gb2      = (const float*)d_in[17];
    const float* emW1     = (const float*)d_in[18];
    const float* emb1     = (const float*)d_in[19];
    const float* emW2     = (const float*)d_in[20];
    const float* emb2     = (const float*)d_in[21];
    const float* oW1      = (const float*)d_in[22];
    const float* ob1      = (const float*)d_in[23];
    const float* oW2      = (const float*)d_in[24];
    const float* ob2      = (const float*)d_in[25];
    const float* oW3      = (const float*)d_in[26];
    const float* ob3      = (const float*)d_in[27];
    float* out = (float*)d_out;

    char* ws = (char*)d_ws;
    float* ve    = (float*)ws;                                   // EDG*40*4 = 20.97 MB
    float* sfull = ve + (size_t)EDG*40;                          // 10 KB
    __hip_bfloat16* W2B   = (__hip_bfloat16*)(sfull + (size_t)NEF*40); // 294,912 B
    __hip_bfloat16* gW1B  = W2B  + (size_t)36*8*512;             // 73,728 B
    __hip_bfloat16* vwW1B = gW1B + (size_t)4*18*512;             // 16,384 B
    int* cnt   = (int*)(vwW1B + (size_t)4*4*512);                // 8 KB
    int* off   = cnt + 2048;
    int* cur   = off + 2049;
    int* slot  = cur + 2048;                                     // 512 KB

    hipMemsetAsync(cnt, 0, 2048*sizeof(int), stream);
    k_hist    <<<EDG/256, 256, 0, stream>>>(att_src, cnt);
    k_scan    <<<1, 1024, 0, stream>>>(cnt, off, cur);
    k_scatter <<<EDG/256, 256, 0, stream>>>(att_src, cur, slot);
    k_cvtW2 <<<(36*8*512 + 255)/256, 256, 0, stream>>>(vw_W2, W2B);
    k_cvtW1s<<<(4*18*512 + 4*4*512 + 255)/256, 256, 0, stream>>>(gW1, vw_W1, gW1B, vwW1B);
    k_scales<<<NEF, 128, 0, stream>>>(e_feat, emW1, emb1, emW2, emb2, sfull);
    k_edge_fused<<<EDG/EPA, 256, 0, stream>>>(h, h_full, z, att_src, att_dst,
        att_dist, att_vec, z_emb_W, slot, vwW1B, vw_b1, gW1B, gb1, gW2, gb2,
        W2B, vw_b2, ve);
    k_out<<<FLAT, 256, 0, stream>>>(ve, off, sfull,
        oW1, ob1, oW2, ob2, oW3, ob3, out);
}

// Round 13
// 602.349 us; speedup vs baseline: 1.0612x; 1.0025x over previous
//
#include <hip/hip_runtime.h>
#include <hip/hip_bf16.h>

#define FLAT   2048
#define EDG    131072
#define NEF    64
#define EPA    32

typedef short  frag8  __attribute__((ext_vector_type(8)));   // 8 bf16 = 4 VGPRs
typedef float  f32x16 __attribute__((ext_vector_type(16)));  // MFMA 32x32 acc

__device__ __forceinline__ float siluf(float x){ return x / (1.f + __expf(-x)); }

__device__ __forceinline__ uint4 pack8(const float v[8]){
    union { uint4 u; __hip_bfloat16 h[8]; } r;
    #pragma unroll
    for (int i=0;i<8;i++) r.h[i] = __float2bfloat16(v[i]);
    return r.u;
}

// ---------------- tiny helpers ----------------
__global__ void k_hist(const int* __restrict__ src, int* __restrict__ cnt){
    int e = blockIdx.x*256 + threadIdx.x;
    if (e < EDG) atomicAdd(&cnt[src[e]], 1);
}

__global__ __launch_bounds__(1024) void k_scan(const int* __restrict__ cnt,
                                               int* __restrict__ off, int* __restrict__ cur){
    __shared__ int s[2048];
    const int tid = threadIdx.x;
    s[tid]      = cnt[tid];
    s[tid+1024] = cnt[tid+1024];
    __syncthreads();
    for (int d=1; d<2048; d<<=1){
        int a = (tid      >= d) ? s[tid      -d] : 0;
        int b = (tid+1024 >= d) ? s[tid+1024 -d] : 0;
        __syncthreads();
        s[tid]      += a;
        s[tid+1024] += b;
        __syncthreads();
    }
    int e0 = (tid==0) ? 0 : s[tid-1];
    int e1 = s[tid+1023];
    off[tid]      = e0;  cur[tid]      = e0;
    off[tid+1024] = e1;  cur[tid+1024] = e1;
    if (tid==0) off[2048] = s[2047];
}

// inverse permutation: slot[e] = CSR position of edge e (src-sorted ve rows)
__global__ void k_scatter(const int* __restrict__ src, int* __restrict__ cur,
                          int* __restrict__ slot){
    int e = blockIdx.x*256 + threadIdx.x;
    if (e < EDG){
        int p = atomicAdd(&cur[src[e]], 1);
        slot[e] = p;
    }
}

// merged prep: blocks [0,576): cvtW2 ; [576,752): cvtW1s ; [752,816): scales
__global__ __launch_bounds__(256) void k_prep(
    const float* __restrict__ W2, __hip_bfloat16* __restrict__ W2B,
    const float* __restrict__ gW1, const float* __restrict__ vwW1,
    __hip_bfloat16* __restrict__ gW1B, __hip_bfloat16* __restrict__ vwW1B,
    const float* __restrict__ eW1, const float* __restrict__ eb1,
    const float* __restrict__ eW2, const float* __restrict__ eb2,
    const float* __restrict__ e_feat, float* __restrict__ sfull)
{
    const int b = blockIdx.x;
    if (b < 576){
        int t = b*256 + threadIdx.x;
        if (t >= 36*8*512) return;
        int j    = t & 7;
        int lane = (t>>3) & 63;
        int cl   = lane & 31, half = lane >> 5;
        int kk   = t >> 9;           // tile*8+ks
        int ks   = kk & 7, tile = kk >> 3;
        int k = ks*16 + half*8 + j;
        int n = tile*32 + cl;
        W2B[t] = __float2bfloat16(W2[(size_t)k*1152 + n]);
    } else if (b < 752){
        int t = (b-576)*256 + threadIdx.x;
        if (t < 4*18*512){
            int j = t & 7;
            int lane = (t>>3) & 63;
            int cl = lane & 31, half = lane >> 5;
            int kk = t >> 9;                 // bb*18+ks
            int ks = kk % 18, bb = kk / 18;
            int k = ks*16 + half*8 + j;
            int c = bb*32 + cl;
            gW1B[t] = __float2bfloat16(k < 273 ? gW1[(size_t)k*128 + c] : 0.f);
        } else if (t < 4*18*512 + 4*4*512){
            int t2 = t - 4*18*512;
            int j = t2 & 7;
            int lane = (t2>>3) & 63;
            int cl = lane & 31, half = lane >> 5;
            int kk = t2 >> 9;                // bb*4+ks
            int ks = kk & 3, bb = kk >> 2;
            int k = ks*16 + half*8 + j;
            int c = bb*32 + cl;
            vwW1B[t2] = __float2bfloat16(k < 49 ? vwW1[(size_t)k*128 + c] : 0.f);
        }
    } else {
        __shared__ float s_e[32];
        __shared__ float s_s[128];
        const int j = b - 752, h = threadIdx.x;
        if (h >= 128) return;
        if (h < 32) s_e[h] = e_feat[j*32+h];
        __syncthreads();
        float a = eb1[h];
        #pragma unroll
        for (int k=0;k<32;k++) a += s_e[k]*eW1[k*128+h];
        s_s[h] = siluf(a);
        __syncthreads();
        if (h < 24){
            float acc = eb2[h];
            #pragma unroll 16
            for (int kk=0;kk<128;kk++) acc += s_s[kk]*eW2[kk*24+h];
            if (h < 16) sfull[j*40+h] = acc;
            else {
                int base = 16 + (h-16)*3;
                sfull[j*40+base+0] = acc;
                sfull[j*40+base+1] = acc;
                sfull[j*40+base+2] = acc;
            }
        }
    }
}

// ---------------- fused edge kernel: prep + W2 GEMM + contraction ----------------
// R12-verified compute (312us). LDS diet to ~28.6KB (target: 5 blocks/CU):
//   t1T (stride 32) overlays s_rbf (dead after S3b); winf overlays s_ve/s_p
//   (zeroed only at S4, after winf's last read in S3a); union = sT+vT only.
// DO NOT: LDS-atomic tile accumulation (R8, 3x slower), register B-dbuf (R1).
__global__ __launch_bounds__(256, 4) void k_edge_fused(
    const float* __restrict__ h_flat, const float* __restrict__ h_full,
    const int* __restrict__ z,
    const int* __restrict__ att_src, const int* __restrict__ att_dst,
    const float* __restrict__ att_dist, const float* __restrict__ att_vec,
    const float* __restrict__ z_emb_W, const int* __restrict__ slot,
    const __hip_bfloat16* __restrict__ vwW1B, const float* __restrict__ vw_b1,
    const __hip_bfloat16* __restrict__ gW1B, const float* __restrict__ gb1,
    const float* __restrict__ gW2, const float* __restrict__ gb2,
    const __hip_bfloat16* __restrict__ W2B, const float* __restrict__ b2,
    float* __restrict__ ve_out)
{
    // persistent
    __shared__ uint4 s_hid4[512];         // 8192 B: hid bf16, fragment order
    __shared__ float s_rbf[EPA][16];      // 2048 B; overlaid by t1T (stride 32) at S5
    __shared__ float s_sh1[EPA][3];
    __shared__ float s_d[EPA], s_env[EPA], s_self[EPA], s_gsum[EPA], s_coef[EPA];
    __shared__ int   s_src[EPA], s_dst[EPA], s_slot[EPA];
    __shared__ float s_ve[EPA][40];       // 5120 B; hosts winf (4096B) until S4
    __shared__ float s_p[EPA][8];         // 1024 B
    // phase union: {ginf_half 576 uint4 = 9216B} / {sT 32x36 + vT 48x36 = 11520B}
    __shared__ uint4 s_uB[720];           // 11520 B

    uint4* s_ginf = s_uB;                 // [576]  (kc half-window)
    uint4* s_winf = (uint4*)&s_ve[0][0];  // [256]  overlay (dead once S4 zeroes s_ve)
    float* s_sT   = (float*)s_uB;         // [32*36]
    float* s_vT   = ((float*)s_uB) + 1152;// [48*36]
    float* s_t1T  = &s_rbf[0][0];         // [16*32] overlay (rbf dead after S3b)
    __hip_bfloat16* s_hid = (__hip_bfloat16*)s_hid4;

    const int tid = threadIdx.x;
    const int e0  = blockIdx.x * EPA;
    const int lane = tid & 63, cl = lane & 31, half = lane >> 5;
    const int wave = tid >> 6;

    // ---- S0: per-edge scalars ----
    if (tid < EPA){
        int e  = e0 + tid;
        int sr = att_src[e], ds = att_dst[e];
        s_src[tid] = sr; s_dst[tid] = ds;
        s_slot[tid] = slot[e];
        float d = att_dist[e];
        s_d[tid] = d;
        float isf = (sr == ds) ? 1.f : 0.f;
        s_self[tid] = isf;
        float dc = fmaxf(d, 1e-8f);
        float ux = att_vec[e*3+0]/dc, uy = att_vec[e*3+1]/dc, uz = att_vec[e*3+2]/dc;
        float m = (isf > 0.f) ? 0.f : 1.7320508075688772f;
        s_sh1[tid][0] = m*uy; s_sh1[tid][1] = m*uz; s_sh1[tid][2] = m*ux;
        s_env[tid] = (d < 5.0f) ? 0.5f*(__cosf(0.6283185307179586f*d)+1.f) : 0.f;
        s_gsum[tid] = gb2[0];
    }
    __syncthreads();

    // ---- S1: rbf ----
    #pragma unroll
    for (int r=0;r<2;r++){
        int t = r*256 + tid; int e = t>>4, jj = t&15;
        float x = (s_d[e] - (float)jj*(1.f/3.f)) * 3.f;
        s_rbf[e][jj] = __expf(-0.5f*x*x);
    }
    __syncthreads();

    // ---- S2a: winf + ginf half A (kc 0..17) ----
    {   // winf: [zemb(32), isf(1), rbf(16), pad->64]
        int m = tid & 31, kc = tid >> 5;
        float v[8];
        if (kc < 4){
            const float* zr = z_emb_W + (size_t)z[s_dst[m]]*32 + kc*8;
            float4 a = *(const float4*)(zr);
            float4 b = *(const float4*)(zr+4);
            v[0]=a.x; v[1]=a.y; v[2]=a.z; v[3]=a.w;
            v[4]=b.x; v[5]=b.y; v[6]=b.z; v[7]=b.w;
        } else if (kc == 4){
            v[0] = s_self[m];
            #pragma unroll
            for (int j=0;j<7;j++) v[1+j] = s_rbf[m][j];
        } else if (kc == 5){
            #pragma unroll
            for (int j=0;j<8;j++) v[j] = s_rbf[m][7+j];
        } else if (kc == 6){
            v[0] = s_rbf[m][15];
            #pragma unroll
            for (int j=1;j<8;j++) v[j] = 0.f;
        } else {
            #pragma unroll
            for (int j=0;j<8;j++) v[j] = 0.f;
        }
        s_winf[kc*32 + m] = pack8(v);
    }
    for (int q = tid; q < 576; q += 256){  // kc 0..15: h_src; 16,17: h_dst chunks 0,1
        int m = q & 31, kc = q >> 5;
        int node = (kc < 16) ? s_src[m] : s_dst[m];
        int koff = (kc & 15)*8;
        const float* hp = h_flat + (size_t)node*128 + koff;
        float4 a = *(const float4*)(hp);
        float4 b = *(const float4*)(hp+4);
        float v[8] = {a.x,a.y,a.z,a.w,b.x,b.y,b.z,b.w};
        s_ginf[kc*32 + m] = pack8(v);
    }
    __syncthreads();

    // ---- S3a: vw GEMM (K=64) -> s_hid ; gate GEMM ks 0..8 ----
    const int c = wave*32 + cl;
    {
        f32x16 acc;
        float bias = vw_b1[c];
        #pragma unroll
        for (int i=0;i<16;i++) acc[i] = bias;
        #pragma unroll
        for (int ks=0;ks<4;ks++){
            frag8 afr = *((const frag8*)&s_winf[(ks*2+half)*32 + cl]);
            frag8 bfr = *(const frag8*)(vwW1B + ((size_t)(wave*4+ks)*64 + lane)*8);
            acc = __builtin_amdgcn_mfma_f32_32x32x16_bf16(afr, bfr, acc, 0, 0, 0);
        }
        __hip_bfloat16* hb = s_hid + (c>>4)*512 + ((c>>3)&1)*256 + (c&7);
        #pragma unroll
        for (int r=0;r<16;r++){
            int e = 4*half + (r&3) + 8*(r>>2);
            hb[e*8] = __float2bfloat16(siluf(acc[r]));
        }
    }
    f32x16 gacc;
    {
        float bias = gb1[c];
        #pragma unroll
        for (int i=0;i<16;i++) gacc[i] = bias;
        #pragma unroll
        for (int ks=0;ks<9;ks++){          // kc 0..17
            frag8 afr = *((const frag8*)&s_ginf[(ks*2+half)*32 + cl]);
            frag8 bfr = *(const frag8*)(gW1B + ((size_t)(wave*18+ks)*64 + lane)*8);
            gacc = __builtin_amdgcn_mfma_f32_32x32x16_bf16(afr, bfr, gacc, 0, 0, 0);
        }
    }
    __syncthreads();

    // ---- S2b: ginf half B (kc 18..35) ----
    for (int q = tid; q < 576; q += 256){
        int m = q & 31, kc2 = q >> 5;      // row kc2 <-> kc = kc2+18
        int kc = kc2 + 18;
        float v[8];
        if (kc < 32){                      // h_dst chunks 2..15
            int koff = (kc & 15)*8;
            const float* hp = h_flat + (size_t)s_dst[m]*128 + koff;
            float4 a = *(const float4*)(hp);
            float4 b = *(const float4*)(hp+4);
            v[0]=a.x; v[1]=a.y; v[2]=a.z; v[3]=a.w;
            v[4]=b.x; v[5]=b.y; v[6]=b.z; v[7]=b.w;
        } else if (kc == 32){
            #pragma unroll
            for (int j=0;j<8;j++) v[j] = s_rbf[m][j];
        } else if (kc == 33){
            #pragma unroll
            for (int j=0;j<8;j++) v[j] = s_rbf[m][8+j];
        } else if (kc == 34){
            v[0] = s_self[m];
            #pragma unroll
            for (int j=1;j<8;j++) v[j] = 0.f;
        } else {
            #pragma unroll
            for (int j=0;j<8;j++) v[j] = 0.f;
        }
        s_ginf[kc2*32 + m] = pack8(v);
    }
    __syncthreads();

    // ---- S3b: gate GEMM ks 9..17 + reduce ----
    {
        #pragma unroll
        for (int ks=9;ks<18;ks++){         // kc 18..35 -> row kc-18
            frag8 afr = *((const frag8*)&s_ginf[((ks*2+half)-18)*32 + cl]);
            frag8 bfr = *(const frag8*)(gW1B + ((size_t)(wave*18+ks)*64 + lane)*8);
            gacc = __builtin_amdgcn_mfma_f32_32x32x16_bf16(afr, bfr, gacc, 0, 0, 0);
        }
        float w2 = gW2[c];
        #pragma unroll
        for (int r=0;r<16;r++){
            float p = siluf(gacc[r]) * w2;
            p += __shfl_down(p, 16, 32);
            p += __shfl_down(p,  8, 32);
            p += __shfl_down(p,  4, 32);
            p += __shfl_down(p,  2, 32);
            p += __shfl_down(p,  1, 32);
            if (cl == 0){
                int e = 4*half + (r&3) + 8*(r>>2);
                atomicAdd(&s_gsum[e], p);
            }
        }
    }
    __syncthreads();   // hid + gsum ready; rbf & winf dead; s_uB free

    // ---- S4: coeff; build sT/vT (union reuse); zero accumulators ----
    if (tid < EPA){
        float gate = 1.f/(1.f+__expf(-s_gsum[tid]));
        s_coef[tid] = s_env[tid]*gate;
    }
    #pragma unroll
    for (int r=0;r<4;r++){
        int t = r*256+tid; int u = t&31, e = t>>5;
        s_sT[u*36+e] = h_full[(size_t)s_dst[e]*80 + u];
    }
    #pragma unroll
    for (int r=0;r<6;r++){
        int t = r*256+tid; int q = t%48, e = t/48;
        s_vT[q*36+e] = h_full[(size_t)s_dst[e]*80 + 32 + q];
    }
    for (int t=tid; t<EPA*48; t+=256){
        int e = t/48, k = t%48;
        if (k < 40) s_ve[e][k] = 0.f; else s_p[e][k-40] = 0.f;
    }
    __syncthreads();

    // ---- S5: t1T from vT (t1T overlays rbf; stride 32) ----
    #pragma unroll
    for (int r=0;r<2;r++){
        int t = r*256+tid; int u = t>>5, e = t&31;
        s_t1T[u*32+e] = s_vT[(u*3+0)*36+e]*s_sh1[e][0]
                      + s_vT[(u*3+1)*36+e]*s_sh1[e][1]
                      + s_vT[(u*3+2)*36+e]*s_sh1[e][2];
    }
    __syncthreads();

    // ---- S6: W2 tile GEMMs + register contraction; af read from LDS per tile ----
    const int eoff = 4*half;
    const float RSQ3 = 0.5773502691896258f;
    const int  Tmain    = wave*8;
    const bool hasExtra = (wave >= 2);
    const int  Textra   = (wave==2) ? 32 : 34;
    const frag8* ap = (const frag8*)s_hid + half*32 + cl;   // + ks*64 per step

    auto mfma_tile = [&](int T)->f32x16{
        float bias = b2[T*32 + cl];
        f32x16 acc;
        #pragma unroll
        for (int q=0;q<16;q++) acc[q] = bias;
        const frag8* wb = (const frag8*)(W2B + (size_t)T*4096 + lane*8);
        #pragma unroll
        for (int ks=0;ks<8;ks++){
            frag8 bfr = wb[ks*64];
            frag8 afr = ap[ks*64];
            acc = __builtin_amdgcn_mfma_f32_32x32x16_bf16(afr, bfr, acc, 0, 0, 0);
        }
        return acc;
    };

    {
        float racc[16];
        #pragma unroll
        for (int r=0;r<16;r++) racc[r] = 0.f;
        #pragma unroll 1
        for (int i=0; i<8; ++i){
            int T = Tmain + i;
            f32x16 acc = mfma_tile(T);
            const float* wb;
            if (wave < 2)        wb = &s_sT [(2*T+(cl>>4))*36 + eoff];
            else if (wave == 2)  wb = &s_t1T[(2*i+(cl>>4))*32 + eoff];
            else                 wb = &s_sT [(4*i+(cl>>3))*36 + eoff];
            #pragma unroll
            for (int g=0; g<4; g++){
                float4 w4 = *(const float4*)(wb + 8*g);
                racc[4*g+0] += acc[4*g+0]*w4.x;
                racc[4*g+1] += acc[4*g+1]*w4.y;
                racc[4*g+2] += acc[4*g+2]*w4.z;
                racc[4*g+3] += acc[4*g+3]*w4.w;
            }
        }
        if (wave < 2){
            int v = cl & 15;
            #pragma unroll
            for (int r=0;r<16;r++){
                int e = eoff + (r&3) + 8*(r>>2);
                atomicAdd(&s_ve[e][v], racc[r]);
            }
        } else if (wave == 2){
            int v = cl & 15;
            #pragma unroll
            for (int r=0;r<16;r++){
                int e = eoff + (r&3) + 8*(r>>2);
                atomicAdd(&s_ve[e][v], racc[r]*RSQ3);
            }
        } else {
            int v = cl & 7;
            #pragma unroll
            for (int r=0;r<16;r++){
                int e = eoff + (r&3) + 8*(r>>2);
                atomicAdd(&s_p[e][v], racc[r]);
            }
        }
    }

    // w101 extra phase: i3 outermost, MFMAs recomputed per i3 (no r3 array)
    if (hasExtra){
        const int t0 = (wave==2) ? 0 : 2;
        #pragma unroll 1
        for (int i3=0;i3<3;i3++){
            float racc[16];
            #pragma unroll
            for (int r=0;r<16;r++) racc[r] = 0.f;
            #pragma unroll 1
            for (int tt=0; tt<2; ++tt){
                f32x16 acc = mfma_tile(Textra + tt);
                int u = 4*(t0+tt) + (cl>>3);
                const float* vb = &s_vT[(u*3+i3)*36 + eoff];
                #pragma unroll
                for (int g=0; g<4; g++){
                    float4 w4 = *(const float4*)(vb + 8*g);
                    racc[4*g+0] += acc[4*g+0]*w4.x;
                    racc[4*g+1] += acc[4*g+1]*w4.y;
                    racc[4*g+2] += acc[4*g+2]*w4.z;
                    racc[4*g+3] += acc[4*g+3]*w4.w;
                }
            }
            int v = cl & 7;
            #pragma unroll
            for (int r=0;r<16;r++){
                int e = eoff + (r&3) + 8*(r>>2);
                atomicAdd(&s_ve[e][16+v*3+i3], racc[r]);
            }
        }
    }
    __syncthreads();

    // ---- S7: flush to CSR slot (src-sorted rows) ----
    const float RFAN = 0.14433756729740643f; // 1/sqrt(48)
    #pragma unroll
    for (int r=0;r<5;r++){
        int t = r*256+tid; int e = t/40, s = t%40;
        float val;
        if (s < 16) val = s_ve[e][s];
        else {
            int v = (s-16)/3, i3 = (s-16)%3;
            val = s_p[e][v]*s_sh1[e][i3] + s_ve[e][s];
        }
        ve_out[(size_t)s_slot[e]*40 + s] = val * RFAN * s_coef[e];
    }
}

// ---------------- K2: contiguous gather + output MLP ----------------
__global__ __launch_bounds__(256) void k_out(
    const float* __restrict__ ve, const int* __restrict__ off,
    const float* __restrict__ sfull,
    const float* __restrict__ W1, const float* __restrict__ b1,
    const float* __restrict__ W2, const float* __restrict__ b2,
    const float* __restrict__ W3, const float* __restrict__ b3,
    float* __restrict__ out)
{
    __shared__ float s_part[6][40];
    __shared__ float s_irr[40];
    __shared__ float s_inv[64][24];
    __shared__ float s_x[64][128];

    const int tid = threadIdx.x;
    const int n   = blockIdx.x;

    {
        const int o0 = off[n], o1 = off[n+1];
        int c = tid/40, s = tid - c*40;
        if (c < 6){
            float acc = 0.f;
            for (int i = o0 + c; i < o1; i += 6)
                acc += ve[(size_t)i*40 + s];
            s_part[c][s] = acc;
        }
    }
    __syncthreads();
    if (tid < 40){
        s_irr[tid] = s_part[0][tid]+s_part[1][tid]+s_part[2][tid]
                   + s_part[3][tid]+s_part[4][tid]+s_part[5][tid];
    }
    __syncthreads();

    #pragma unroll
    for (int r=0;r<6;r++){
        int t = r*256+tid; int j = t/24, c = t%24;
        float v;
        if (c < 16) v = s_irr[c]*sfull[j*40+c];
        else {
            int base = 16 + (c-16)*3;
            float ss = 1e-12f;
            #pragma unroll
            for (int i=0;i<3;i++){ float x = s_irr[base+i]*sfull[j*40+base+i]; ss += x*x; }
            v = sqrtf(ss);
        }
        s_inv[j][c] = v;
    }
    __syncthreads();

    const int h4 = (tid & 31)*4, jg = tid >> 5;
    float acc[8][4];

    #pragma unroll
    for (int jj=0;jj<8;jj++)
        #pragma unroll
        for (int hh=0;hh<4;hh++) acc[jj][hh] = b1[h4+hh];
    #pragma unroll
    for (int k=0;k<24;k+=4){
        float4 w0 = *(const float4*)&W1[(k+0)*128+h4];
        float4 w1 = *(const float4*)&W1[(k+1)*128+h4];
        float4 w2 = *(const float4*)&W1[(k+2)*128+h4];
        float4 w3 = *(const float4*)&W1[(k+3)*128+h4];
        #pragma unroll
        for (int jj=0;jj<8;jj++){
            float4 xv = *(const float4*)&s_inv[jg*8+jj][k];
            acc[jj][0] += xv.x*w0.x + xv.y*w1.x + xv.z*w2.x + xv.w*w3.x;
            acc[jj][1] += xv.x*w0.y + xv.y*w1.y + xv.z*w2.y + xv.w*w3.y;
            acc[jj][2] += xv.x*w0.z + xv.y*w1.z + xv.z*w2.z + xv.w*w3.z;
            acc[jj][3] += xv.x*w0.w + xv.y*w1.w + xv.z*w2.w + xv.w*w3.w;
        }
    }
    #pragma unroll
    for (int jj=0;jj<8;jj++)
        *(float4*)&s_x[jg*8+jj][h4] = make_float4(siluf(acc[jj][0]), siluf(acc[jj][1]),
                                                  siluf(acc[jj][2]), siluf(acc[jj][3]));
    __syncthreads();

    #pragma unroll
    for (int jj=0;jj<8;jj++)
        #pragma unroll
        for (int hh=0;hh<4;hh++) acc[jj][hh] = b2[h4+hh];
    for (int k=0;k<128;k+=4){
        float4 w0 = *(const float4*)&W2[(k+0)*128+h4];
        float4 w1 = *(const float4*)&W2[(k+1)*128+h4];
        float4 w2 = *(const float4*)&W2[(k+2)*128+h4];
        float4 w3 = *(const float4*)&W2[(k+3)*128+h4];
        #pragma unroll
        for (int jj=0;jj<8;jj++){
            float4 xv = *(const float4*)&s_x[jg*8+jj][k];
            acc[jj][0] += xv.x*w0.x + xv.y*w1.x + xv.z*w2.x + xv.w*w3.x;
            acc[jj][1] += xv.x*w0.y + xv.y*w1.y + xv.z*w2.y + xv.w*w3.y;
            acc[jj][2] += xv.x*w0.z + xv.y*w1.z + xv.z*w2.z + xv.w*w3.z;
            acc[jj][3] += xv.x*w0.w + xv.y*w1.w + xv.z*w2.w + xv.w*w3.w;
        }
    }
    __syncthreads();
    #pragma unroll
    for (int jj=0;jj<8;jj++)
        *(float4*)&s_x[jg*8+jj][h4] = make_float4(siluf(acc[jj][0]), siluf(acc[jj][1]),
                                                  siluf(acc[jj][2]), siluf(acc[jj][3]));
    __syncthreads();

    #pragma unroll
    for (int jj=0;jj<8;jj++)
        #pragma unroll
        for (int hh=0;hh<4;hh++) acc[jj][hh] = b3[h4+hh];
    for (int k=0;k<128;k+=4){
        float4 w0 = *(const float4*)&W3[(k+0)*128+h4];
        float4 w1 = *(const float4*)&W3[(k+1)*128+h4];
        float4 w2 = *(const float4*)&W3[(k+2)*128+h4];
        float4 w3 = *(const float4*)&W3[(k+3)*128+h4];
        #pragma unroll
        for (int jj=0;jj<8;jj++){
            float4 xv = *(const float4*)&s_x[jg*8+jj][k];
            acc[jj][0] += xv.x*w0.x + xv.y*w1.x + xv.z*w2.x + xv.w*w3.x;
            acc[jj][1] += xv.x*w0.y + xv.y*w1.y + xv.z*w2.y + xv.w*w3.y;
            acc[jj][2] += xv.x*w0.z + xv.y*w1.z + xv.z*w2.z + xv.w*w3.z;
            acc[jj][3] += xv.x*w0.w + xv.y*w1.w + xv.z*w2.w + xv.w*w3.w;
        }
    }
    #pragma unroll
    for (int jj=0;jj<8;jj++){
        int j = jg*8+jj;
        *(float4*)&out[((size_t)n*64 + j)*128 + h4] =
            make_float4(acc[jj][0], acc[jj][1], acc[jj][2], acc[jj][3]);
    }
}

// ---------------- launch ----------------
extern "C" void kernel_launch(void* const* d_in, const int* in_sizes, int n_in,
                              void* d_out, int out_size, void* d_ws, size_t ws_size,
                              hipStream_t stream)
{
    const float* h        = (const float*)d_in[0];
    const float* h_full   = (const float*)d_in[1];
    const float* e_feat   = (const float*)d_in[2];
    const float* att_dist = (const float*)d_in[3];
    const float* att_vec  = (const float*)d_in[4];
    const int*   z        = (const int*)d_in[5];
    const int* att_src    = (const int*)d_in[7];
    const int* att_dst    = (const int*)d_in[8];
    const float* z_emb_W  = (const float*)d_in[9];
    const float* vw_W1    = (const float*)d_in[10];
    const float* vw_b1    = (const float*)d_in[11];
    const float* vw_W2    = (const float*)d_in[12];
    const float* vw_b2    = (const float*)d_in[13];
    const float* gW1      = (const float*)d_in[14];
    const float* gb1      = (const float*)d_in[15];
    const float* gW2      = (const float*)d_in[16];
    const float* gb2      = (const float*)d_in[17];
    const float* emW1     = (const float*)d_in[18];
    const float* emb1     = (const float*)d_in[19];
    const float* emW2     = (const float*)d_in[20];
    const float* emb2     = (const float*)d_in[21];
    const float* oW1      = (const float*)d_in[22];
    const float* ob1      = (const float*)d_in[23];
    const float* oW2      = (const float*)d_in[24];
    const float* ob2      = (const float*)d_in[25];
    const float* oW3      = (const float*)d_in[26];
    const float* ob3      = (const float*)d_in[27];
    float* out = (float*)d_out;

    char* ws = (char*)d_ws;
    float* ve    = (float*)ws;                                   // EDG*40*4 = 20.97 MB
    float* sfull = ve + (size_t)EDG*40;                          // 10 KB
    __hip_bfloat16* W2B   = (__hip_bfloat16*)(sfull + (size_t)NEF*40); // 294,912 B
    __hip_bfloat16* gW1B  = W2B  + (size_t)36*8*512;             // 73,728 B
    __hip_bfloat16* vwW1B = gW1B + (size_t)4*18*512;             // 16,384 B
    int* cnt   = (int*)(vwW1B + (size_t)4*4*512);                // 8 KB
    int* off   = cnt + 2048;
    int* cur   = off + 2049;
    int* slot  = cur + 2048;                                     // 512 KB

    hipMemsetAsync(cnt, 0, 2048*sizeof(int), stream);
    k_hist    <<<EDG/256, 256, 0, stream>>>(att_src, cnt);
    k_scan    <<<1, 1024, 0, stream>>>(cnt, off, cur);
    k_scatter <<<EDG/256, 256, 0, stream>>>(att_src, cur, slot);
    k_prep    <<<816, 256, 0, stream>>>(vw_W2, W2B, gW1, vw_W1, gW1B, vwW1B,
                                        emW1, emb1, emW2, emb2, e_feat, sfull);
    k_edge_fused<<<EDG/EPA, 256, 0, stream>>>(h, h_full, z, att_src, att_dst,
        att_dist, att_vec, z_emb_W, slot, vwW1B, vw_b1, gW1B, gb1, gW2, gb2,
        W2B, vw_b2, ve);
    k_out<<<FLAT, 256, 0, stream>>>(ve, off, sfull,
        oW1, ob1, oW2, ob2, oW3, ob3, out);
}

// Round 14
// 601.207 us; speedup vs baseline: 1.0632x; 1.0019x over previous
//
#include <hip/hip_runtime.h>
#include <hip/hip_bf16.h>

#define FLAT   2048
#define EDG    131072
#define NEF    64
#define EPA    32

typedef short  frag8  __attribute__((ext_vector_type(8)));   // 8 bf16 = 4 VGPRs
typedef float  f32x16 __attribute__((ext_vector_type(16)));  // MFMA 32x32 acc

__device__ __forceinline__ float siluf(float x){ return x / (1.f + __expf(-x)); }

__device__ __forceinline__ uint4 pack8(const float v[8]){
    union { uint4 u; __hip_bfloat16 h[8]; } r;
    #pragma unroll
    for (int i=0;i<8;i++) r.h[i] = __float2bfloat16(v[i]);
    return r.u;
}

// ---------------- tiny helpers ----------------
__global__ void k_hist(const int* __restrict__ src, int* __restrict__ cnt){
    int e = blockIdx.x*256 + threadIdx.x;
    if (e < EDG) atomicAdd(&cnt[src[e]], 1);
}

__global__ __launch_bounds__(1024) void k_scan(const int* __restrict__ cnt,
                                               int* __restrict__ off, int* __restrict__ cur){
    __shared__ int s[2048];
    const int tid = threadIdx.x;
    s[tid]      = cnt[tid];
    s[tid+1024] = cnt[tid+1024];
    __syncthreads();
    for (int d=1; d<2048; d<<=1){
        int a = (tid      >= d) ? s[tid      -d] : 0;
        int b = (tid+1024 >= d) ? s[tid+1024 -d] : 0;
        __syncthreads();
        s[tid]      += a;
        s[tid+1024] += b;
        __syncthreads();
    }
    int e0 = (tid==0) ? 0 : s[tid-1];
    int e1 = s[tid+1023];
    off[tid]      = e0;  cur[tid]      = e0;
    off[tid+1024] = e1;  cur[tid+1024] = e1;
    if (tid==0) off[2048] = s[2047];
}

// inverse permutation: slot[e] = CSR position of edge e (src-sorted ve rows)
__global__ void k_scatter(const int* __restrict__ src, int* __restrict__ cur,
                          int* __restrict__ slot){
    int e = blockIdx.x*256 + threadIdx.x;
    if (e < EDG){
        int p = atomicAdd(&cur[src[e]], 1);
        slot[e] = p;
    }
}

// merged prep: blocks [0,576): cvtW2 ; [576,752): cvtW1s ; [752,816): scales
__global__ __launch_bounds__(256) void k_prep(
    const float* __restrict__ W2, __hip_bfloat16* __restrict__ W2B,
    const float* __restrict__ gW1, const float* __restrict__ vwW1,
    __hip_bfloat16* __restrict__ gW1B, __hip_bfloat16* __restrict__ vwW1B,
    const float* __restrict__ eW1, const float* __restrict__ eb1,
    const float* __restrict__ eW2, const float* __restrict__ eb2,
    const float* __restrict__ e_feat, float* __restrict__ sfull)
{
    const int b = blockIdx.x;
    if (b < 576){
        int t = b*256 + threadIdx.x;
        if (t >= 36*8*512) return;
        int j    = t & 7;
        int lane = (t>>3) & 63;
        int cl   = lane & 31, half = lane >> 5;
        int kk   = t >> 9;           // tile*8+ks
        int ks   = kk & 7, tile = kk >> 3;
        int k = ks*16 + half*8 + j;
        int n = tile*32 + cl;
        W2B[t] = __float2bfloat16(W2[(size_t)k*1152 + n]);
    } else if (b < 752){
        int t = (b-576)*256 + threadIdx.x;
        if (t < 4*18*512){
            int j = t & 7;
            int lane = (t>>3) & 63;
            int cl = lane & 31, half = lane >> 5;
            int kk = t >> 9;                 // bb*18+ks
            int ks = kk % 18, bb = kk / 18;
            int k = ks*16 + half*8 + j;
            int c = bb*32 + cl;
            gW1B[t] = __float2bfloat16(k < 273 ? gW1[(size_t)k*128 + c] : 0.f);
        } else if (t < 4*18*512 + 4*4*512){
            int t2 = t - 4*18*512;
            int j = t2 & 7;
            int lane = (t2>>3) & 63;
            int cl = lane & 31, half = lane >> 5;
            int kk = t2 >> 9;                // bb*4+ks
            int ks = kk & 3, bb = kk >> 2;
            int k = ks*16 + half*8 + j;
            int c = bb*32 + cl;
            vwW1B[t2] = __float2bfloat16(k < 49 ? vwW1[(size_t)k*128 + c] : 0.f);
        }
    } else {
        __shared__ float s_e[32];
        __shared__ float s_s[128];
        const int j = b - 752, h = threadIdx.x;
        if (h >= 128) return;
        if (h < 32) s_e[h] = e_feat[j*32+h];
        __syncthreads();
        float a = eb1[h];
        #pragma unroll
        for (int k=0;k<32;k++) a += s_e[k]*eW1[k*128+h];
        s_s[h] = siluf(a);
        __syncthreads();
        if (h < 24){
            float acc = eb2[h];
            #pragma unroll 16
            for (int kk=0;kk<128;kk++) acc += s_s[kk]*eW2[kk*24+h];
            if (h < 16) sfull[j*40+h] = acc;
            else {
                int base = 16 + (h-16)*3;
                sfull[j*40+base+0] = acc;
                sfull[j*40+base+1] = acc;
                sfull[j*40+base+2] = acc;
            }
        }
    }
}

// ---------------- fused edge kernel: prep + W2 GEMM + contraction ----------------
// R13 body, ONE change: no min-waves clamp. With af in LDS the live set is ~50
// regs; freeing the allocator past 64 lets it keep next-tile B-fragments in
// flight (the pipelining the (256,4) cap forbade). LDS 29696 still fits 5/CU.
// DO NOT: LDS-atomic tile accumulation (R8, 3x slower); watch WRITE_SIZE for
// spill regression (should stay ~20.8MB).
__global__ __launch_bounds__(256) void k_edge_fused(
    const float* __restrict__ h_flat, const float* __restrict__ h_full,
    const int* __restrict__ z,
    const int* __restrict__ att_src, const int* __restrict__ att_dst,
    const float* __restrict__ att_dist, const float* __restrict__ att_vec,
    const float* __restrict__ z_emb_W, const int* __restrict__ slot,
    const __hip_bfloat16* __restrict__ vwW1B, const float* __restrict__ vw_b1,
    const __hip_bfloat16* __restrict__ gW1B, const float* __restrict__ gb1,
    const float* __restrict__ gW2, const float* __restrict__ gb2,
    const __hip_bfloat16* __restrict__ W2B, const float* __restrict__ b2,
    float* __restrict__ ve_out)
{
    // persistent
    __shared__ uint4 s_hid4[512];         // 8192 B: hid bf16, fragment order
    __shared__ float s_rbf[EPA][16];      // 2048 B; overlaid by t1T (stride 32) at S5
    __shared__ float s_sh1[EPA][3];
    __shared__ float s_d[EPA], s_env[EPA], s_self[EPA], s_gsum[EPA], s_coef[EPA];
    __shared__ int   s_src[EPA], s_dst[EPA], s_slot[EPA];
    __shared__ float s_ve[EPA][40];       // 5120 B; hosts winf (4096B) until S4
    __shared__ float s_p[EPA][8];         // 1024 B
    // phase union: {ginf_half 576 uint4 = 9216B} / {sT 32x36 + vT 48x36 = 11520B}
    __shared__ uint4 s_uB[720];           // 11520 B

    uint4* s_ginf = s_uB;                 // [576]  (kc half-window)
    uint4* s_winf = (uint4*)&s_ve[0][0];  // [256]  overlay (dead once S4 zeroes s_ve)
    float* s_sT   = (float*)s_uB;         // [32*36]
    float* s_vT   = ((float*)s_uB) + 1152;// [48*36]
    float* s_t1T  = &s_rbf[0][0];         // [16*32] overlay (rbf dead after S3b)
    __hip_bfloat16* s_hid = (__hip_bfloat16*)s_hid4;

    const int tid = threadIdx.x;
    const int e0  = blockIdx.x * EPA;
    const int lane = tid & 63, cl = lane & 31, half = lane >> 5;
    const int wave = tid >> 6;

    // ---- S0: per-edge scalars ----
    if (tid < EPA){
        int e  = e0 + tid;
        int sr = att_src[e], ds = att_dst[e];
        s_src[tid] = sr; s_dst[tid] = ds;
        s_slot[tid] = slot[e];
        float d = att_dist[e];
        s_d[tid] = d;
        float isf = (sr == ds) ? 1.f : 0.f;
        s_self[tid] = isf;
        float dc = fmaxf(d, 1e-8f);
        float ux = att_vec[e*3+0]/dc, uy = att_vec[e*3+1]/dc, uz = att_vec[e*3+2]/dc;
        float m = (isf > 0.f) ? 0.f : 1.7320508075688772f;
        s_sh1[tid][0] = m*uy; s_sh1[tid][1] = m*uz; s_sh1[tid][2] = m*ux;
        s_env[tid] = (d < 5.0f) ? 0.5f*(__cosf(0.6283185307179586f*d)+1.f) : 0.f;
        s_gsum[tid] = gb2[0];
    }
    __syncthreads();

    // ---- S1: rbf ----
    #pragma unroll
    for (int r=0;r<2;r++){
        int t = r*256 + tid; int e = t>>4, jj = t&15;
        float x = (s_d[e] - (float)jj*(1.f/3.f)) * 3.f;
        s_rbf[e][jj] = __expf(-0.5f*x*x);
    }
    __syncthreads();

    // ---- S2a: winf + ginf half A (kc 0..17) ----
    {   // winf: [zemb(32), isf(1), rbf(16), pad->64]
        int m = tid & 31, kc = tid >> 5;
        float v[8];
        if (kc < 4){
            const float* zr = z_emb_W + (size_t)z[s_dst[m]]*32 + kc*8;
            float4 a = *(const float4*)(zr);
            float4 b = *(const float4*)(zr+4);
            v[0]=a.x; v[1]=a.y; v[2]=a.z; v[3]=a.w;
            v[4]=b.x; v[5]=b.y; v[6]=b.z; v[7]=b.w;
        } else if (kc == 4){
            v[0] = s_self[m];
            #pragma unroll
            for (int j=0;j<7;j++) v[1+j] = s_rbf[m][j];
        } else if (kc == 5){
            #pragma unroll
            for (int j=0;j<8;j++) v[j] = s_rbf[m][7+j];
        } else if (kc == 6){
            v[0] = s_rbf[m][15];
            #pragma unroll
            for (int j=1;j<8;j++) v[j] = 0.f;
        } else {
            #pragma unroll
            for (int j=0;j<8;j++) v[j] = 0.f;
        }
        s_winf[kc*32 + m] = pack8(v);
    }
    for (int q = tid; q < 576; q += 256){  // kc 0..15: h_src; 16,17: h_dst chunks 0,1
        int m = q & 31, kc = q >> 5;
        int node = (kc < 16) ? s_src[m] : s_dst[m];
        int koff = (kc & 15)*8;
        const float* hp = h_flat + (size_t)node*128 + koff;
        float4 a = *(const float4*)(hp);
        float4 b = *(const float4*)(hp+4);
        float v[8] = {a.x,a.y,a.z,a.w,b.x,b.y,b.z,b.w};
        s_ginf[kc*32 + m] = pack8(v);
    }
    __syncthreads();

    // ---- S3a: vw GEMM (K=64) -> s_hid ; gate GEMM ks 0..8 ----
    const int c = wave*32 + cl;
    {
        f32x16 acc;
        float bias = vw_b1[c];
        #pragma unroll
        for (int i=0;i<16;i++) acc[i] = bias;
        #pragma unroll
        for (int ks=0;ks<4;ks++){
            frag8 afr = *((const frag8*)&s_winf[(ks*2+half)*32 + cl]);
            frag8 bfr = *(const frag8*)(vwW1B + ((size_t)(wave*4+ks)*64 + lane)*8);
            acc = __builtin_amdgcn_mfma_f32_32x32x16_bf16(afr, bfr, acc, 0, 0, 0);
        }
        __hip_bfloat16* hb = s_hid + (c>>4)*512 + ((c>>3)&1)*256 + (c&7);
        #pragma unroll
        for (int r=0;r<16;r++){
            int e = 4*half + (r&3) + 8*(r>>2);
            hb[e*8] = __float2bfloat16(siluf(acc[r]));
        }
    }
    f32x16 gacc;
    {
        float bias = gb1[c];
        #pragma unroll
        for (int i=0;i<16;i++) gacc[i] = bias;
        #pragma unroll
        for (int ks=0;ks<9;ks++){          // kc 0..17
            frag8 afr = *((const frag8*)&s_ginf[(ks*2+half)*32 + cl]);
            frag8 bfr = *(const frag8*)(gW1B + ((size_t)(wave*18+ks)*64 + lane)*8);
            gacc = __builtin_amdgcn_mfma_f32_32x32x16_bf16(afr, bfr, gacc, 0, 0, 0);
        }
    }
    __syncthreads();

    // ---- S2b: ginf half B (kc 18..35) ----
    for (int q = tid; q < 576; q += 256){
        int m = q & 31, kc2 = q >> 5;      // row kc2 <-> kc = kc2+18
        int kc = kc2 + 18;
        float v[8];
        if (kc < 32){                      // h_dst chunks 2..15
            int koff = (kc & 15)*8;
            const float* hp = h_flat + (size_t)s_dst[m]*128 + koff;
            float4 a = *(const float4*)(hp);
            float4 b = *(const float4*)(hp+4);
            v[0]=a.x; v[1]=a.y; v[2]=a.z; v[3]=a.w;
            v[4]=b.x; v[5]=b.y; v[6]=b.z; v[7]=b.w;
        } else if (kc == 32){
            #pragma unroll
            for (int j=0;j<8;j++) v[j] = s_rbf[m][j];
        } else if (kc == 33){
            #pragma unroll
            for (int j=0;j<8;j++) v[j] = s_rbf[m][8+j];
        } else if (kc == 34){
            v[0] = s_self[m];
            #pragma unroll
            for (int j=1;j<8;j++) v[j] = 0.f;
        } else {
            #pragma unroll
            for (int j=0;j<8;j++) v[j] = 0.f;
        }
        s_ginf[kc2*32 + m] = pack8(v);
    }
    __syncthreads();

    // ---- S3b: gate GEMM ks 9..17 + reduce ----
    {
        #pragma unroll
        for (int ks=9;ks<18;ks++){         // kc 18..35 -> row kc-18
            frag8 afr = *((const frag8*)&s_ginf[((ks*2+half)-18)*32 + cl]);
            frag8 bfr = *(const frag8*)(gW1B + ((size_t)(wave*18+ks)*64 + lane)*8);
            gacc = __builtin_amdgcn_mfma_f32_32x32x16_bf16(afr, bfr, gacc, 0, 0, 0);
        }
        float w2 = gW2[c];
        #pragma unroll
        for (int r=0;r<16;r++){
            float p = siluf(gacc[r]) * w2;
            p += __shfl_down(p, 16, 32);
            p += __shfl_down(p,  8, 32);
            p += __shfl_down(p,  4, 32);
            p += __shfl_down(p,  2, 32);
            p += __shfl_down(p,  1, 32);
            if (cl == 0){
                int e = 4*half + (r&3) + 8*(r>>2);
                atomicAdd(&s_gsum[e], p);
            }
        }
    }
    __syncthreads();   // hid + gsum ready; rbf & winf dead; s_uB free

    // ---- S4: coeff; build sT/vT (union reuse); zero accumulators ----
    if (tid < EPA){
        float gate = 1.f/(1.f+__expf(-s_gsum[tid]));
        s_coef[tid] = s_env[tid]*gate;
    }
    #pragma unroll
    for (int r=0;r<4;r++){
        int t = r*256+tid; int u = t&31, e = t>>5;
        s_sT[u*36+e] = h_full[(size_t)s_dst[e]*80 + u];
    }
    #pragma unroll
    for (int r=0;r<6;r++){
        int t = r*256+tid; int q = t%48, e = t/48;
        s_vT[q*36+e] = h_full[(size_t)s_dst[e]*80 + 32 + q];
    }
    for (int t=tid; t<EPA*48; t+=256){
        int e = t/48, k = t%48;
        if (k < 40) s_ve[e][k] = 0.f; else s_p[e][k-40] = 0.f;
    }
    __syncthreads();

    // ---- S5: t1T from vT (t1T overlays rbf; stride 32) ----
    #pragma unroll
    for (int r=0;r<2;r++){
        int t = r*256+tid; int u = t>>5, e = t&31;
        s_t1T[u*32+e] = s_vT[(u*3+0)*36+e]*s_sh1[e][0]
                      + s_vT[(u*3+1)*36+e]*s_sh1[e][1]
                      + s_vT[(u*3+2)*36+e]*s_sh1[e][2];
    }
    __syncthreads();

    // ---- S6: W2 tile GEMMs + register contraction; af read from LDS per tile ----
    const int eoff = 4*half;
    const float RSQ3 = 0.5773502691896258f;
    const int  Tmain    = wave*8;
    const bool hasExtra = (wave >= 2);
    const int  Textra   = (wave==2) ? 32 : 34;
    const frag8* ap = (const frag8*)s_hid + half*32 + cl;   // + ks*64 per step

    auto mfma_tile = [&](int T)->f32x16{
        float bias = b2[T*32 + cl];
        f32x16 acc;
        #pragma unroll
        for (int q=0;q<16;q++) acc[q] = bias;
        const frag8* wb = (const frag8*)(W2B + (size_t)T*4096 + lane*8);
        #pragma unroll
        for (int ks=0;ks<8;ks++){
            frag8 bfr = wb[ks*64];
            frag8 afr = ap[ks*64];
            acc = __builtin_amdgcn_mfma_f32_32x32x16_bf16(afr, bfr, acc, 0, 0, 0);
        }
        return acc;
    };

    {
        float racc[16];
        #pragma unroll
        for (int r=0;r<16;r++) racc[r] = 0.f;
        #pragma unroll 1
        for (int i=0; i<8; ++i){
            int T = Tmain + i;
            f32x16 acc = mfma_tile(T);
            const float* wb;
            if (wave < 2)        wb = &s_sT [(2*T+(cl>>4))*36 + eoff];
            else if (wave == 2)  wb = &s_t1T[(2*i+(cl>>4))*32 + eoff];
            else                 wb = &s_sT [(4*i+(cl>>3))*36 + eoff];
            #pragma unroll
            for (int g=0; g<4; g++){
                float4 w4 = *(const float4*)(wb + 8*g);
                racc[4*g+0] += acc[4*g+0]*w4.x;
                racc[4*g+1] += acc[4*g+1]*w4.y;
                racc[4*g+2] += acc[4*g+2]*w4.z;
                racc[4*g+3] += acc[4*g+3]*w4.w;
            }
        }
        if (wave < 2){
            int v = cl & 15;
            #pragma unroll
            for (int r=0;r<16;r++){
                int e = eoff + (r&3) + 8*(r>>2);
                atomicAdd(&s_ve[e][v], racc[r]);
            }
        } else if (wave == 2){
            int v = cl & 15;
            #pragma unroll
            for (int r=0;r<16;r++){
                int e = eoff + (r&3) + 8*(r>>2);
                atomicAdd(&s_ve[e][v], racc[r]*RSQ3);
            }
        } else {
            int v = cl & 7;
            #pragma unroll
            for (int r=0;r<16;r++){
                int e = eoff + (r&3) + 8*(r>>2);
                atomicAdd(&s_p[e][v], racc[r]);
            }
        }
    }

    // w101 extra phase: i3 outermost, MFMAs recomputed per i3 (no r3 array)
    if (hasExtra){
        const int t0 = (wave==2) ? 0 : 2;
        #pragma unroll 1
        for (int i3=0;i3<3;i3++){
            float racc[16];
            #pragma unroll
            for (int r=0;r<16;r++) racc[r] = 0.f;
            #pragma unroll 1
            for (int tt=0; tt<2; ++tt){
                f32x16 acc = mfma_tile(Textra + tt);
                int u = 4*(t0+tt) + (cl>>3);
                const float* vb = &s_vT[(u*3+i3)*36 + eoff];
                #pragma unroll
                for (int g=0; g<4; g++){
                    float4 w4 = *(const float4*)(vb + 8*g);
                    racc[4*g+0] += acc[4*g+0]*w4.x;
                    racc[4*g+1] += acc[4*g+1]*w4.y;
                    racc[4*g+2] += acc[4*g+2]*w4.z;
                    racc[4*g+3] += acc[4*g+3]*w4.w;
                }
            }
            int v = cl & 7;
            #pragma unroll
            for (int r=0;r<16;r++){
                int e = eoff + (r&3) + 8*(r>>2);
                atomicAdd(&s_ve[e][16+v*3+i3], racc[r]);
            }
        }
    }
    __syncthreads();

    // ---- S7: flush to CSR slot (src-sorted rows) ----
    const float RFAN = 0.14433756729740643f; // 1/sqrt(48)
    #pragma unroll
    for (int r=0;r<5;r++){
        int t = r*256+tid; int e = t/40, s = t%40;
        float val;
        if (s < 16) val = s_ve[e][s];
        else {
            int v = (s-16)/3, i3 = (s-16)%3;
            val = s_p[e][v]*s_sh1[e][i3] + s_ve[e][s];
        }
        ve_out[(size_t)s_slot[e]*40 + s] = val * RFAN * s_coef[e];
    }
}

// ---------------- K2: contiguous gather + output MLP ----------------
__global__ __launch_bounds__(256) void k_out(
    const float* __restrict__ ve, const int* __restrict__ off,
    const float* __restrict__ sfull,
    const float* __restrict__ W1, const float* __restrict__ b1,
    const float* __restrict__ W2, const float* __restrict__ b2,
    const float* __restrict__ W3, const float* __restrict__ b3,
    float* __restrict__ out)
{
    __shared__ float s_part[6][40];
    __shared__ float s_irr[40];
    __shared__ float s_inv[64][24];
    __shared__ float s_x[64][128];

    const int tid = threadIdx.x;
    const int n   = blockIdx.x;

    {
        const int o0 = off[n], o1 = off[n+1];
        int c = tid/40, s = tid - c*40;
        if (c < 6){
            float acc = 0.f;
            for (int i = o0 + c; i < o1; i += 6)
                acc += ve[(size_t)i*40 + s];
            s_part[c][s] = acc;
        }
    }
    __syncthreads();
    if (tid < 40){
        s_irr[tid] = s_part[0][tid]+s_part[1][tid]+s_part[2][tid]
                   + s_part[3][tid]+s_part[4][tid]+s_part[5][tid];
    }
    __syncthreads();

    #pragma unroll
    for (int r=0;r<6;r++){
        int t = r*256+tid; int j = t/24, c = t%24;
        float v;
        if (c < 16) v = s_irr[c]*sfull[j*40+c];
        else {
            int base = 16 + (c-16)*3;
            float ss = 1e-12f;
            #pragma unroll
            for (int i=0;i<3;i++){ float x = s_irr[base+i]*sfull[j*40+base+i]; ss += x*x; }
            v = sqrtf(ss);
        }
        s_inv[j][c] = v;
    }
    __syncthreads();

    const int h4 = (tid & 31)*4, jg = tid >> 5;
    float acc[8][4];

    #pragma unroll
    for (int jj=0;jj<8;jj++)
        #pragma unroll
        for (int hh=0;hh<4;hh++) acc[jj][hh] = b1[h4+hh];
    #pragma unroll
    for (int k=0;k<24;k+=4){
        float4 w0 = *(const float4*)&W1[(k+0)*128+h4];
        float4 w1 = *(const float4*)&W1[(k+1)*128+h4];
        float4 w2 = *(const float4*)&W1[(k+2)*128+h4];
        float4 w3 = *(const float4*)&W1[(k+3)*128+h4];
        #pragma unroll
        for (int jj=0;jj<8;jj++){
            float4 xv = *(const float4*)&s_inv[jg*8+jj][k];
            acc[jj][0] += xv.x*w0.x + xv.y*w1.x + xv.z*w2.x + xv.w*w3.x;
            acc[jj][1] += xv.x*w0.y + xv.y*w1.y + xv.z*w2.y + xv.w*w3.y;
            acc[jj][2] += xv.x*w0.z + xv.y*w1.z + xv.z*w2.z + xv.w*w3.z;
            acc[jj][3] += xv.x*w0.w + xv.y*w1.w + xv.z*w2.w + xv.w*w3.w;
        }
    }
    #pragma unroll
    for (int jj=0;jj<8;jj++)
        *(float4*)&s_x[jg*8+jj][h4] = make_float4(siluf(acc[jj][0]), siluf(acc[jj][1]),
                                                  siluf(acc[jj][2]), siluf(acc[jj][3]));
    __syncthreads();

    #pragma unroll
    for (int jj=0;jj<8;jj++)
        #pragma unroll
        for (int hh=0;hh<4;hh++) acc[jj][hh] = b2[h4+hh];
    for (int k=0;k<128;k+=4){
        float4 w0 = *(const float4*)&W2[(k+0)*128+h4];
        float4 w1 = *(const float4*)&W2[(k+1)*128+h4];
        float4 w2 = *(const float4*)&W2[(k+2)*128+h4];
        float4 w3 = *(const float4*)&W2[(k+3)*128+h4];
        #pragma unroll
        for (int jj=0;jj<8;jj++){
            float4 xv = *(const float4*)&s_x[jg*8+jj][k];
            acc[jj][0] += xv.x*w0.x + xv.y*w1.x + xv.z*w2.x + xv.w*w3.x;
            acc[jj][1] += xv.x*w0.y + xv.y*w1.y + xv.z*w2.y + xv.w*w3.y;
            acc[jj][2] += xv.x*w0.z + xv.y*w1.z + xv.z*w2.z + xv.w*w3.z;
            acc[jj][3] += xv.x*w0.w + xv.y*w1.w + xv.z*w2.w + xv.w*w3.w;
        }
    }
    __syncthreads();
    #pragma unroll
    for (int jj=0;jj<8;jj++)
        *(float4*)&s_x[jg*8+jj][h4] = make_float4(siluf(acc[jj][0]), siluf(acc[jj][1]),
                                                  siluf(acc[jj][2]), siluf(acc[jj][3]));
    __syncthreads();

    #pragma unroll
    for (int jj=0;jj<8;jj++)
        #pragma unroll
        for (int hh=0;hh<4;hh++) acc[jj][hh] = b3[h4+hh];
    for (int k=0;k<128;k+=4){
        float4 w0 = *(const float4*)&W3[(k+0)*128+h4];
        float4 w1 = *(const float4*)&W3[(k+1)*128+h4];
        float4 w2 = *(const float4*)&W3[(k+2)*128+h4];
        float4 w3 = *(const float4*)&W3[(k+3)*128+h4];
        #pragma unroll
        for (int jj=0;jj<8;jj++){
            float4 xv = *(const float4*)&s_x[jg*8+jj][k];
            acc[jj][0] += xv.x*w0.x + xv.y*w1.x + xv.z*w2.x + xv.w*w3.x;
            acc[jj][1] += xv.x*w0.y + xv.y*w1.y + xv.z*w2.y + xv.w*w3.y;
            acc[jj][2] += xv.x*w0.z + xv.y*w1.z + xv.z*w2.z + xv.w*w3.z;
            acc[jj][3] += xv.x*w0.w + xv.y*w1.w + xv.z*w2.w + xv.w*w3.w;
        }
    }
    #pragma unroll
    for (int jj=0;jj<8;jj++){
        int j = jg*8+jj;
        *(float4*)&out[((size_t)n*64 + j)*128 + h4] =
            make_float4(acc[jj][0], acc[jj][1], acc[jj][2], acc[jj][3]);
    }
}

// ---------------- launch ----------------
extern "C" void kernel_launch(void* const* d_in, const int* in_sizes, int n_in,
                              void* d_out, int out_size, void* d_ws, size_t ws_size,
                              hipStream_t stream)
{
    const float* h        = (const float*)d_in[0];
    const float* h_full   = (const float*)d_in[1];
    const float* e_feat   = (const float*)d_in[2];
    const float* att_dist = (const float*)d_in[3];
    const float* att_vec  = (const float*)d_in[4];
    const int*   z        = (const int*)d_in[5];
    const int* att_src    = (const int*)d_in[7];
    const int* att_dst    = (const int*)d_in[8];
    const float* z_emb_W  = (const float*)d_in[9];
    const float* vw_W1    = (const float*)d_in[10];
    const float* vw_b1    = (const float*)d_in[11];
    const float* vw_W2    = (const float*)d_in[12];
    const float* vw_b2    = (const float*)d_in[13];
    const float* gW1      = (const float*)d_in[14];
    const float* gb1      = (const float*)d_in[15];
    const float* gW2      = (const float*)d_in[16];
    const float* gb2      = (const float*)d_in[17];
    const float* emW1     = (const float*)d_in[18];
    const float* emb1     = (const float*)d_in[19];
    const float* emW2     = (const float*)d_in[20];
    const float* emb2     = (const float*)d_in[21];
    const float* oW1      = (const float*)d_in[22];
    const float* ob1      = (const float*)d_in[23];
    const float* oW2      = (const float*)d_in[24];
    const float* ob2      = (const float*)d_in[25];
    const float* oW3      = (const float*)d_in[26];
    const float* ob3      = (const float*)d_in[27];
    float* out = (float*)d_out;

    char* ws = (char*)d_ws;
    float* ve    = (float*)ws;                                   // EDG*40*4 = 20.97 MB
    float* sfull = ve + (size_t)EDG*40;                          // 10 KB
    __hip_bfloat16* W2B   = (__hip_bfloat16*)(sfull + (size_t)NEF*40); // 294,912 B
    __hip_bfloat16* gW1B  = W2B  + (size_t)36*8*512;             // 73,728 B
    __hip_bfloat16* vwW1B = gW1B + (size_t)4*18*512;             // 16,384 B
    int* cnt   = (int*)(vwW1B + (size_t)4*4*512);                // 8 KB
    int* off   = cnt + 2048;
    int* cur   = off + 2049;
    int* slot  = cur + 2048;                                     // 512 KB

    hipMemsetAsync(cnt, 0, 2048*sizeof(int), stream);
    k_hist    <<<EDG/256, 256, 0, stream>>>(att_src, cnt);
    k_scan    <<<1, 1024, 0, stream>>>(cnt, off, cur);
    k_scatter <<<EDG/256, 256, 0, stream>>>(att_src, cur, slot);
    k_prep    <<<816, 256, 0, stream>>>(vw_W2, W2B, gW1, vw_W1, gW1B, vwW1B,
                                        emW1, emb1, emW2, emb2, e_feat, sfull);
    k_edge_fused<<<EDG/EPA, 256, 0, stream>>>(h, h_full, z, att_src, att_dst,
        att_dist, att_vec, z_emb_W, slot, vwW1B, vw_b1, gW1B, gb1, gW2, gb2,
        W2B, vw_b2, ve);
    k_out<<<FLAT, 256, 0, stream>>>(ve, off, sfull,
        oW1, ob1, oW2, ob2, oW3, ob3, out);
}